// Round 12
// baseline (1298.552 us; speedup 1.0000x reference)
//
#include <hip/hip_runtime.h>
#include <math.h>

#define NN 20000
#define NP 20096           // NN padded to 128 (157 tiles)
#define EE 320000
#define GG 64
#define IN_F 256
#define NC 16
#define NSTEPS 4
#define KT 4
#define TOTKV (KT*NP)      // 80384 = 157 * 512
#define NBLK 157

typedef unsigned int uint;
typedef unsigned short ushort;
typedef __attribute__((ext_vector_type(2))) float f2;
typedef __attribute__((ext_vector_type(4))) float f4;
typedef __attribute__((ext_vector_type(4))) ushort u16x4;
typedef __attribute__((ext_vector_type(8))) ushort u16x8;
typedef __attribute__((ext_vector_type(8))) short s16x8;

#define GLD_LDS(gp, lp) __builtin_amdgcn_global_load_lds( \
    (const __attribute__((address_space(1))) void*)(gp),  \
    (__attribute__((address_space(3))) void*)(lp), 16, 0, 0)

__device__ __forceinline__ ushort f2b(float f) {
    uint u = __float_as_uint(f);
    u = (u + 0x7FFFu + ((u >> 16) & 1u)) >> 16;   // RNE f32->bf16
    return (ushort)u;
}
__device__ __forceinline__ float b2f(ushort s) { return __uint_as_float(((uint)s) << 16); }
__device__ __forceinline__ float sgm(float x) { return 1.f / (1.f + __expf(-x)); }
__device__ __forceinline__ float ftanh(float x) { return 2.f / (1.f + __expf(-2.f * x)) - 1.f; }

// XCD-aware work swizzle: all GX work-columns of a node-tile y land on one XCD
// (assumes flat-id % 8 round-robin). y rows >=152 (tail of 157) map linearly.
__device__ __forceinline__ void sw_xy(int GX, int& x, int& y) {
    int f = blockIdx.x + GX * blockIdx.y;
    int body = GX * 152;                 // 19 groups of 8 y-rows
    if (f < body) {
        int xcd = f & 7, j = f >> 3;
        x = j % GX;
        y = (j / GX) * 8 + xcd;
    } else {
        int r = f - body;
        x = r % GX;
        y = 152 + r / GX;
    }
}

// ---------- weight prep ----------
// WT[k][o][d] <- Wmsg[k][d][o], LDS-tiled 32x32 so both sides coalesce
__global__ void conv_msgT(const float* __restrict__ Wm, ushort* __restrict__ WT) {
    __shared__ ushort sh[32][33];
    int k = blockIdx.z;
    int d0 = blockIdx.x * 32, o0 = blockIdx.y * 32;
    int tx = threadIdx.x & 31, ty = threadIdx.x >> 5;   // ty 0..7
#pragma unroll
    for (int i = 0; i < 4; i++) {
        int d = d0 + ty + i * 8;
        sh[ty + i * 8][tx] = f2b(Wm[((size_t)k << 18) + (size_t)d * 512 + o0 + tx]);
    }
    __syncthreads();
#pragma unroll
    for (int i = 0; i < 4; i++) {
        int o = o0 + ty + i * 8;
        WT[((size_t)k << 18) + (size_t)o * 512 + d0 + tx] = sh[tx][ty + i * 8];
    }
}
__global__ void conv_copy(const float* __restrict__ x, ushort* __restrict__ y, int n) {
    int i = blockIdx.x * 256 + threadIdx.x;
    if (i < n) y[i] = f2b(x[i]);
}
// Wrz[o2][k2]: o2<512 -> r-gate rows, o2>=512 -> z-gate; k2<512 from w_ih, else w_hh
__global__ void build_wrz(const float* __restrict__ wih, const float* __restrict__ whh,
                          ushort* __restrict__ W) {
    int idx = blockIdx.x * 256 + threadIdx.x;
    if (idx >= 1024 * 1024) return;
    int o2 = idx >> 10, k2 = idx & 1023;
    int gate = o2 >> 9, o = o2 & 511;
    float v = (k2 < 512) ? wih[(gate * 512 + o) * 512 + k2]
                         : whh[(gate * 512 + o) * 512 + (k2 - 512)];
    W[idx] = f2b(v);
}

// ---------- CSR build (etype-major, dst-minor) ----------
__global__ void count_edges(const int* __restrict__ etype, const int* __restrict__ dst,
                            int* __restrict__ cnt) {
    int e = blockIdx.x * 256 + threadIdx.x;
    if (e >= EE) return;
    atomicAdd(&cnt[etype[e] * NP + dst[e]], 1);
}
__global__ __launch_bounds__(512) void scan_blk(const int* __restrict__ cnt,
                                                int* __restrict__ offs,
                                                float* __restrict__ cntf,
                                                int* __restrict__ bsum) {
    __shared__ int sh[512];
    int t = threadIdx.x, b = blockIdx.x;
    int i = b * 512 + t;
    int v = cnt[i];
    sh[t] = v; __syncthreads();
    for (int off = 1; off < 512; off <<= 1) {
        int add = (t >= off) ? sh[t - off] : 0;
        __syncthreads();
        sh[t] += add;
        __syncthreads();
    }
    offs[i] = sh[t] - v;         // local exclusive
    cntf[i] = (float)v;
    if (t == 511) bsum[b] = sh[511];
}
__global__ void scan_top(const int* __restrict__ bsum, int* __restrict__ boff,
                         int* __restrict__ offs) {
    if (threadIdx.x == 0) {
        int run = 0;
        for (int i = 0; i < NBLK; i++) { boff[i] = run; run += bsum[i]; }
        offs[TOTKV] = run;
    }
}
__global__ __launch_bounds__(512) void scan_add(int* __restrict__ offs,
                                                const int* __restrict__ boff) {
    int i = blockIdx.x * 512 + threadIdx.x;
    offs[i] += boff[blockIdx.x];
}
__global__ void fill_edges(const int* __restrict__ etype, const int* __restrict__ dst,
                           const int* __restrict__ src, int* __restrict__ cursor,
                           int* __restrict__ srcs_s, int* __restrict__ dsts_s) {
    int e = blockIdx.x * 256 + threadIdx.x;
    if (e >= EE) return;
    int pos = atomicAdd(&cursor[etype[e] * NP + dst[e]], 1);
    srcs_s[pos] = src[e];
    dsts_s[pos] = dst[e];
}

// ---------- pad input -> bf16 h (zeros for d>=256 and rows>=NN) ----------
__global__ void pad2(const float* __restrict__ in_feat, ushort* __restrict__ h) {
    int idx = blockIdx.x * 256 + threadIdx.x;   // one per 8 elems
    if (idx >= NP * 64) return;
    int n = idx >> 6, o = (idx & 63) * 8;
    u16x8 ov = {0,0,0,0,0,0,0,0};
    if (n < NN && o < IN_F) {
        f4 a = *(const f4*)(in_feat + (size_t)n * IN_F + o);
        f4 b = *(const f4*)(in_feat + (size_t)n * IN_F + o + 4);
        ov = (u16x8){ f2b(a[0]), f2b(a[1]), f2b(a[2]), f2b(a[3]),
                      f2b(b[0]), f2b(b[1]), f2b(b[2]), f2b(b[3]) };
    }
    *(u16x8*)(h + (size_t)n * 512 + o) = ov;
}

// ---------- gather for k-pair, 4-deep load pipelining ----------
__global__ void gather2(const int* __restrict__ offs, const int* __restrict__ srcs,
                        const ushort* __restrict__ hin, ushort* __restrict__ S2, int kp) {
    int wv = threadIdx.x >> 6, lane = threadIdx.x & 63;
    int r = blockIdx.x * 4 + wv;                 // [0, 2*NP)
    int kl = (r >= NP) ? 1 : 0;
    int v = r - kl * NP;
    int k = kp * 2 + kl;
    int beg = offs[k * NP + v], end = offs[k * NP + v + 1];
    float acc[8] = {0,0,0,0,0,0,0,0};
    int e = beg;
    for (; e + 4 <= end; e += 4) {
        int s0 = srcs[e], s1 = srcs[e + 1], s2 = srcs[e + 2], s3 = srcs[e + 3];
        u16x8 h0 = *(const u16x8*)(hin + (size_t)s0 * 512 + lane * 8);
        u16x8 h1 = *(const u16x8*)(hin + (size_t)s1 * 512 + lane * 8);
        u16x8 h2 = *(const u16x8*)(hin + (size_t)s2 * 512 + lane * 8);
        u16x8 h3 = *(const u16x8*)(hin + (size_t)s3 * 512 + lane * 8);
#pragma unroll
        for (int j = 0; j < 8; j++)
            acc[j] += (b2f(h0[j]) + b2f(h1[j])) + (b2f(h2[j]) + b2f(h3[j]));
    }
    if (e + 2 <= end) {
        int s0 = srcs[e], s1 = srcs[e + 1];
        u16x8 h0 = *(const u16x8*)(hin + (size_t)s0 * 512 + lane * 8);
        u16x8 h1 = *(const u16x8*)(hin + (size_t)s1 * 512 + lane * 8);
#pragma unroll
        for (int j = 0; j < 8; j++) acc[j] += b2f(h0[j]) + b2f(h1[j]);
        e += 2;
    }
    if (e < end) {
        int s0 = srcs[e];
        u16x8 h0 = *(const u16x8*)(hin + (size_t)s0 * 512 + lane * 8);
#pragma unroll
        for (int j = 0; j < 8; j++) acc[j] += b2f(h0[j]);
    }
    u16x8 ov;
#pragma unroll
    for (int j = 0; j < 8; j++) ov[j] = f2b(acc[j]);
    *(u16x8*)(S2 + ((size_t)kl * NP + v) * 512 + lane * 8) = ov;
}

// ---------- shared MFMA GEMM body: 128x128 tile, global_load_lds + XOR swizzle ----------
// C[node][o] = sum_k B[node][k] * W[o][k], K split at KtA between (Wa,Ba) and (Wb,Bb).
// B matrices stride 512. flags: 1 = accumulate bf16 C; 2 = add sum_k cntf*bmsg
__device__ __forceinline__ void gemm_body(
    ushort* As, ushort* Bs,
    const ushort* __restrict__ Wa, const ushort* __restrict__ Wb, int swA,
    const ushort* __restrict__ Ba, const ushort* __restrict__ Bb,
    int KtA, int Kt, ushort* __restrict__ C, int ldC, int o0, int n0, int flags,
    const float* __restrict__ cntf, const float* __restrict__ bmsg) {
    int t = threadIdx.x;
    int wave = t >> 6, lane = t & 63;
    int wm = wave & 1, wn = wave >> 1;
    int l16 = lane & 15, quad = lane >> 4;
    f4 acc[4][4];
#pragma unroll
    for (int i = 0; i < 4; i++)
#pragma unroll
        for (int j = 0; j < 4; j++) acc[i][j] = (f4){0,0,0,0};
    for (int kk = 0; kk < Kt; kk += 64) {
        const ushort* Wsrc = (kk < KtA) ? Wa : Wb;
        const ushort* Bsrc = (kk < KtA) ? Ba : Bb;
        int ko = (kk < KtA) ? kk : kk - KtA;
#pragma unroll
        for (int i = 0; i < 4; i++) {
            int c = i * 256 + t;                  // LDS 16B slot id, 0..1023
            int row = c >> 3, pc = c & 7;         // physical chunk pc
            int gcol = ((pc ^ (row & 7)) << 3);   // XOR swizzle: source logical chunk
            int ldsoff = (i * 256 + wave * 64) * 8;   // wave-uniform, lane*16B added by HW
            GLD_LDS(Wsrc + (size_t)(o0 + row) * swA + ko + gcol, As + ldsoff);
            GLD_LDS(Bsrc + (size_t)(n0 + row) * 512 + ko + gcol, Bs + ldsoff);
        }
        __syncthreads();
#pragma unroll
        for (int ks = 0; ks < 64; ks += 32) {
            s16x8 af[4], bf[4];
            int j = (ks >> 3) + quad;             // logical chunk
#pragma unroll
            for (int mi = 0; mi < 4; mi++) {
                int R = wm*64 + mi*16 + l16;
                af[mi] = *(const s16x8*)&As[R * 64 + ((j ^ (R & 7)) << 3)];
            }
#pragma unroll
            for (int ni = 0; ni < 4; ni++) {
                int R = wn*64 + ni*16 + l16;
                bf[ni] = *(const s16x8*)&Bs[R * 64 + ((j ^ (R & 7)) << 3)];
            }
#pragma unroll
            for (int mi = 0; mi < 4; mi++)
#pragma unroll
                for (int ni = 0; ni < 4; ni++)
                    acc[mi][ni] = __builtin_amdgcn_mfma_f32_16x16x32_bf16(af[mi], bf[ni], acc[mi][ni], 0, 0, 0);
        }
        __syncthreads();
    }
#pragma unroll
    for (int ni = 0; ni < 4; ni++) {
        int node = n0 + wn*64 + ni*16 + l16;
#pragma unroll
        for (int mi = 0; mi < 4; mi++) {
            int o = o0 + wm*64 + mi*16 + quad*4;
            f4 v = acc[mi][ni];
            if (flags & 2) {
#pragma unroll
                for (int k = 0; k < KT; k++) {
                    float ck = cntf[k * NP + node];
                    f4 bm = *(const f4*)(bmsg + k * 512 + o);
                    v += ck * bm;
                }
            }
            ushort* cp = C + (size_t)node * ldC + o;
            if (flags & 1) {
                u16x4 old = *(const u16x4*)cp;
                v += (f4){ b2f(old[0]), b2f(old[1]), b2f(old[2]), b2f(old[3]) };
            }
            u16x4 ov = { f2b(v[0]), f2b(v[1]), f2b(v[2]), f2b(v[3]) };
            *(u16x4*)cp = ov;
        }
    }
}

// grid: x = output chunk, y = node tile (XCD-swizzled)
__global__ __launch_bounds__(256, 3) void gemm2(
    const ushort* Wa, const ushort* Wb, int swA,
    const ushort* Ba, const ushort* Bb, int KtA, int Kt,
    ushort* C, int ldC, int flags,
    const float* cntf, const float* bmsg) {
    __shared__ ushort As[128 * 64];
    __shared__ ushort Bs[128 * 64];
    int x, y; sw_xy(gridDim.x, x, y);
    gemm_body(As, Bs, Wa, Wb, swA, Ba, Bb, KtA, Kt, C, ldC,
              x * 128, y * 128, flags, cntf, bmsg);
}

// merged rz + hn dispatch: x<8 -> rz (M=1024), x>=8 -> hn (M=512)
__global__ __launch_bounds__(256, 3) void gemm_rzhn(
    const ushort* wrz, const ushort* whn,
    const ushort* abf, const ushort* hin,
    ushort* rzout, ushort* hnout, int ktRZ, int ktHN) {
    __shared__ ushort As[128 * 64];
    __shared__ ushort Bs[128 * 64];
    int x, y; sw_xy(gridDim.x, x, y);
    if (x < 8) {
        gemm_body(As, Bs, wrz, wrz + 512, 1024, abf, hin, 512, ktRZ,
                  rzout, 1024, x * 128, y * 128, 0, nullptr, nullptr);
    } else {
        gemm_body(As, Bs, whn, whn, 512, hin, hin, 512, ktHN,
                  hnout, 512, (x - 8) * 128, y * 128, 0, nullptr, nullptr);
    }
}

// ---------- i_n GEMM with fused GRU epilogue ----------
__global__ __launch_bounds__(256, 3) void gemm_gru(
    const ushort* __restrict__ W, const ushort* __restrict__ Bm,
    const ushort* __restrict__ rz, const ushort* __restrict__ hin,
    const float* __restrict__ b_ih, const float* __restrict__ b_hh,
    ushort* __restrict__ hnb) {
    __shared__ ushort As[128 * 64];
    __shared__ ushort Bs[128 * 64];
    int t = threadIdx.x;
    int x, y; sw_xy(gridDim.x, x, y);
    int o0 = x * 128, n0 = y * 128;
    int wave = t >> 6, lane = t & 63;
    int wm = wave & 1, wn = wave >> 1;
    int l16 = lane & 15, quad = lane >> 4;
    f4 acc[4][4];
#pragma unroll
    for (int i = 0; i < 4; i++)
#pragma unroll
        for (int j = 0; j < 4; j++) acc[i][j] = (f4){0,0,0,0};
    for (int kk = 0; kk < 512; kk += 64) {
#pragma unroll
        for (int i = 0; i < 4; i++) {
            int c = i * 256 + t;
            int row = c >> 3, pc = c & 7;
            int gcol = ((pc ^ (row & 7)) << 3);
            int ldsoff = (i * 256 + wave * 64) * 8;
            GLD_LDS(W + (size_t)(o0 + row) * 512 + kk + gcol, As + ldsoff);
            GLD_LDS(Bm + (size_t)(n0 + row) * 512 + kk + gcol, Bs + ldsoff);
        }
        __syncthreads();
#pragma unroll
        for (int ks = 0; ks < 64; ks += 32) {
            s16x8 af[4], bf[4];
            int j = (ks >> 3) + quad;
#pragma unroll
            for (int mi = 0; mi < 4; mi++) {
                int R = wm*64 + mi*16 + l16;
                af[mi] = *(const s16x8*)&As[R * 64 + ((j ^ (R & 7)) << 3)];
            }
#pragma unroll
            for (int ni = 0; ni < 4; ni++) {
                int R = wn*64 + ni*16 + l16;
                bf[ni] = *(const s16x8*)&Bs[R * 64 + ((j ^ (R & 7)) << 3)];
            }
#pragma unroll
            for (int mi = 0; mi < 4; mi++)
#pragma unroll
                for (int ni = 0; ni < 4; ni++)
                    acc[mi][ni] = __builtin_amdgcn_mfma_f32_16x16x32_bf16(af[mi], bf[ni], acc[mi][ni], 0, 0, 0);
        }
        __syncthreads();
    }
    // epilogue: mi outer so the 6 bias vectors load once per output column group
#pragma unroll
    for (int mi = 0; mi < 4; mi++) {
        int o = o0 + wm*64 + mi*16 + quad*4;
        f4 bi0 = *(const f4*)(b_ih + o);
        f4 bi1 = *(const f4*)(b_ih + 512 + o);
        f4 bi2 = *(const f4*)(b_ih + 1024 + o);
        f4 bh0 = *(const f4*)(b_hh + o);
        f4 bh1 = *(const f4*)(b_hh + 512 + o);
        f4 bh2 = *(const f4*)(b_hh + 1024 + o);
#pragma unroll
        for (int ni = 0; ni < 4; ni++) {
            int node = n0 + wn*64 + ni*16 + l16;
            u16x4 rz1 = *(const u16x4*)(rz + (size_t)node * 1024 + o);
            u16x4 rz2 = *(const u16x4*)(rz + (size_t)node * 1024 + 512 + o);
            u16x4 hnv = *(const u16x4*)(hnb + (size_t)node * 512 + o);
            u16x4 hol = *(const u16x4*)(hin + (size_t)node * 512 + o);
            u16x4 ov;
#pragma unroll
            for (int r = 0; r < 4; r++) {
                float rg = sgm(b2f(rz1[r]) + bi0[r] + bh0[r]);
                float zg = sgm(b2f(rz2[r]) + bi1[r] + bh1[r]);
                float nv = ftanh(acc[mi][ni][r] + bi2[r] + rg * (b2f(hnv[r]) + bh2[r]));
                ov[r] = f2b((1.f - zg) * nv + zg * b2f(hol[r]));
            }
            *(u16x4*)(hnb + (size_t)node * 512 + o) = ov;
        }
    }
}

// ---------- L2 normalize + sigmoid (bf16 in/out), one wave per node ----------
__global__ void norm_sig(ushort* __restrict__ h) {
    int n = blockIdx.x, lane = threadIdx.x;   // 64 threads
    u16x8 v = *(const u16x8*)(h + (size_t)n * 512 + lane * 8);
    float f[8], ss = 0.f;
#pragma unroll
    for (int j = 0; j < 8; j++) { f[j] = b2f(v[j]); ss += f[j] * f[j]; }
    for (int off = 32; off > 0; off >>= 1) ss += __shfl_xor(ss, off);
    float inv = 1.f / fmaxf(sqrtf(ss), 1e-12f);
    u16x8 ov;
#pragma unroll
    for (int j = 0; j < 8; j++) ov[j] = f2b(sgm(f[j] * inv));
    *(u16x8*)(h + (size_t)n * 512 + lane * 8) = ov;
}

// ---------- el/er from bf16 feat, one wave per node ----------
__global__ void el_er2(const ushort* __restrict__ feat, const float* __restrict__ attn_l,
                       const float* __restrict__ attn_r, float* __restrict__ el,
                       float* __restrict__ er) {
    int n = blockIdx.x, lane = threadIdx.x;   // 64
    int head = lane >> 5;
    int ld = (lane * 8) & 255;
    u16x8 v = *(const u16x8*)(feat + (size_t)n * 512 + lane * 8);
    float sl = 0.f, sr = 0.f;
#pragma unroll
    for (int j = 0; j < 8; j++) {
        float f = b2f(v[j]);
        sl += f * attn_l[head * 256 + ld + j];
        sr += f * attn_r[head * 256 + ld + j];
    }
    for (int off = 16; off > 0; off >>= 1) { sl += __shfl_xor(sl, off); sr += __shfl_xor(sr, off); }
    if ((lane & 31) == 0) { el[n * 2 + head] = sl; er[n * 2 + head] = sr; }
}

// ---------- per-CSR-slot edge scores (leaky relu), both heads ----------
__global__ void edge_scores(const int* __restrict__ srcs, const int* __restrict__ dsts,
                            const float* __restrict__ el, const float* __restrict__ er,
                            float* __restrict__ esc) {
    int e = blockIdx.x * 256 + threadIdx.x;
    if (e >= EE) return;
    int s = srcs[e], d = dsts[e];
    f2 elv = *(const f2*)(el + (size_t)s * 2);
    f2 erv = *(const f2*)(er + (size_t)d * 2);
    float s0 = elv[0] + erv[0]; s0 = s0 < 0.f ? 0.2f * s0 : s0;
    float s1 = elv[1] + erv[1]; s1 = s1 < 0.f ? 0.2f * s1 : s1;
    *(f2*)(esc + (size_t)e * 2) = (f2){ s0, s1 };
}

// ---------- fused GAT: softmax over in-edges + aggregation + bias/relu, rst f32 out (no atomics) ----------
__global__ void gat3(const int* __restrict__ offs, const int* __restrict__ srcs,
                     const float* __restrict__ esc, const ushort* __restrict__ feat,
                     const float* __restrict__ gat_bias, float* __restrict__ rst) {
    int wave = threadIdx.x >> 6, lane = threadIdx.x & 63;
    int v = blockIdx.x * 4 + wave;
    int beg[KT], end[KT];
#pragma unroll
    for (int k = 0; k < KT; k++) { beg[k] = offs[k * NP + v]; end[k] = offs[k * NP + v + 1]; }
    float m0 = -1e30f, m1 = -1e30f;
#pragma unroll
    for (int k = 0; k < KT; k++)
        for (int base = beg[k]; base < end[k]; base += 64) {
            int e = base + lane;
            if (e < end[k]) {
                f2 s = *(const f2*)(esc + (size_t)e * 2);
                m0 = fmaxf(m0, s[0]); m1 = fmaxf(m1, s[1]);
            }
        }
    for (int off = 32; off > 0; off >>= 1) {
        m0 = fmaxf(m0, __shfl_xor(m0, off));
        m1 = fmaxf(m1, __shfl_xor(m1, off));
    }
    float d0 = 0.f, d1 = 0.f;
#pragma unroll
    for (int k = 0; k < KT; k++)
        for (int base = beg[k]; base < end[k]; base += 64) {
            int e = base + lane;
            if (e < end[k]) {
                f2 s = *(const f2*)(esc + (size_t)e * 2);
                d0 += __expf(s[0] - m0); d1 += __expf(s[1] - m1);
            }
        }
    for (int off = 32; off > 0; off >>= 1) { d0 += __shfl_xor(d0, off); d1 += __shfl_xor(d1, off); }
    int head = lane >> 5;
    float mm = head ? m1 : m0;
    float iv = head ? (d1 > 0.f ? 1.f / d1 : 0.f) : (d0 > 0.f ? 1.f / d0 : 0.f);
    float acc[8] = {0,0,0,0,0,0,0,0};
#pragma unroll
    for (int k = 0; k < KT; k++)
        for (int e = beg[k]; e < end[k]; e++) {
            float sc = esc[(size_t)e * 2 + head];
            float al = __expf(sc - mm) * iv;
            u16x8 fv = *(const u16x8*)(feat + (size_t)srcs[e] * 512 + lane * 8);
#pragma unroll
            for (int j = 0; j < 8; j++) acc[j] += al * b2f(fv[j]);
        }
    int di = lane * 8;
    f4 o0, o1;
#pragma unroll
    for (int j = 0; j < 4; j++) {
        o0[j] = fmaxf(acc[j] + gat_bias[di + j], 0.f);
        o1[j] = fmaxf(acc[4 + j] + gat_bias[di + 4 + j], 0.f);
    }
    *(f4*)(rst + (size_t)v * 512 + di) = o0;
    *(f4*)(rst + (size_t)v * 512 + di + 4) = o1;
}

// ---------- graph boundaries via binary search on sorted graph_ids ----------
__global__ void graph_bounds(const int* __restrict__ gids, int* __restrict__ goff) {
    int g = threadIdx.x;   // 128 threads, need 0..64
    if (g > GG) return;
    int lo = 0, hi = NN;
    while (lo < hi) { int mid = (lo + hi) >> 1; if (gids[mid] < g) lo = mid + 1; else hi = mid; }
    goff[g] = lo;
}

// ---------- per-graph partial sums of rst -> hgm (atomic, 8 chunks/graph) ----------
__global__ void graph_mean2(const float* __restrict__ rst, const int* __restrict__ goff,
                            float* __restrict__ hgm) {
    int g = blockIdx.x, yc = blockIdx.y, t = threadIdx.x;
    int beg = goff[g], end = goff[g + 1];
    float s0 = 0.f, s1 = 0.f;
    for (int n = beg + yc; n < end; n += 8) {
        s0 += rst[(size_t)n * 512 + t];
        s1 += rst[(size_t)n * 512 + 256 + t];
    }
    atomicAdd(&hgm[g * 512 + t], s0);
    atomicAdd(&hgm[g * 512 + 256 + t], s1);
}

// ---------- classify (divides by graph size) ----------
__global__ void classify(const float* __restrict__ hgm, const int* __restrict__ goff,
                         const float* __restrict__ cw, const float* __restrict__ cb,
                         float* __restrict__ out) {
    __shared__ float hl[512];
    int g = blockIdx.x, t = threadIdx.x;  // 64 threads
    int cntn = goff[g + 1] - goff[g];
    float inv = (cntn > 0) ? 1.f / (float)cntn : 0.f;
    for (int d = t; d < 512; d += 64) hl[d] = hgm[g * 512 + d] * inv;
    __syncthreads();
    if (t < 32) {
        int hd = t >> 4, c = t & 15;
        float acc = 0.f;
        for (int d = 0; d < 256; d++) acc += hl[hd * 256 + d] * cw[c * 256 + d];
        out[(g * 2 + hd) * NC + c] = acc + cb[c];
    }
}

static inline int cdiv(int a, int b) { return (a + b - 1) / b; }
static inline size_t alup(size_t x) { return (x + 255) & ~(size_t)255; }

extern "C" void kernel_launch(void* const* d_in, const int* in_sizes, int n_in,
                              void* d_out, int out_size, void* d_ws, size_t ws_size,
                              hipStream_t stream) {
    const float* in_feat   = (const float*)d_in[0];
    const int*   src       = (const int*)d_in[1];
    const int*   dst       = (const int*)d_in[2];
    const int*   etype     = (const int*)d_in[3];
    const int*   graph_ids = (const int*)d_in[4];
    const float* Wmsg      = (const float*)d_in[5];
    const float* bmsg      = (const float*)d_in[6];
    const float* w_ih      = (const float*)d_in[7];
    const float* w_hh      = (const float*)d_in[8];
    const float* b_ih      = (const float*)d_in[9];
    const float* b_hh      = (const float*)d_in[10];
    const float* fc_w      = (const float*)d_in[11];
    const float* attn_l    = (const float*)d_in[12];
    const float* attn_r    = (const float*)d_in[13];
    const float* gat_bias  = (const float*)d_in[14];
    const float* cw        = (const float*)d_in[15];
    const float* cb        = (const float*)d_in[16];
    float* out = (float*)d_out;

    char* p = (char*)d_ws;
    ushort* hbfA  = (ushort*)p; p += alup((size_t)NP * 512 * 2);
    ushort* hbfB  = (ushort*)p; p += alup((size_t)NP * 512 * 2);
    ushort* abf   = (ushort*)p; p += alup((size_t)NP * 512 * 2);
    ushort* S2    = (ushort*)p; p += alup((size_t)2 * NP * 512 * 2);  // gathered S pair / rz (NP x 1024) / rst f32
    ushort* wmsgT = (ushort*)p; p += alup((size_t)KT * 512 * 512 * 2);
    ushort* wihb  = (ushort*)p; p += alup((size_t)1536 * 512 * 2);
    ushort* whhb  = (ushort*)p; p += alup((size_t)1536 * 512 * 2);
    ushort* wrz   = (ushort*)p; p += alup((size_t)1024 * 1024 * 2);
    ushort* fcb   = (ushort*)p; p += alup((size_t)512 * 512 * 2);
    int*    cnt   = (int*)p;    p += alup((size_t)TOTKV * 4);
    int*    offs  = (int*)p;    p += alup(((size_t)TOTKV + 1) * 4);
    int*    cursor= (int*)p;    p += alup(((size_t)TOTKV + 1) * 4);
    float*  cntf  = (float*)p;  p += alup((size_t)TOTKV * 4);
    int*    bsum  = (int*)p;    p += alup((size_t)NBLK * 4);
    int*    boff  = (int*)p;    p += alup((size_t)NBLK * 4);
    int*    srcs_s= (int*)p;    p += alup((size_t)EE * 4);
    int*    dsts_s= (int*)p;    p += alup((size_t)EE * 4);
    float*  esc   = (float*)p;  p += alup((size_t)EE * 2 * 4);
    float*  el    = (float*)p;  p += alup((size_t)NN * 2 * 4);
    float*  er    = (float*)p;  p += alup((size_t)NN * 2 * 4);
    int*    goff  = (int*)p;    p += alup((size_t)(GG + 1) * 4);
    float*  hgm   = (float*)p;  p += alup((size_t)GG * 512 * 4);
    ushort* featbf = abf;          // alias: abf free after last gemm_gru
    float*  rst    = (float*)S2;   // alias: rz region free after last gemm_gru (same byte size)

    // ---- weight prep ----
    conv_msgT<<<dim3(16, 16, 4), 256, 0, stream>>>(Wmsg, wmsgT);
    conv_copy<<<cdiv(1536 * 512, 256), 256, 0, stream>>>(w_ih, wihb, 1536 * 512);
    conv_copy<<<cdiv(1536 * 512, 256), 256, 0, stream>>>(w_hh, whhb, 1536 * 512);
    build_wrz<<<cdiv(1024 * 1024, 256), 256, 0, stream>>>(w_ih, w_hh, wrz);
    conv_copy<<<cdiv(512 * 512, 256), 256, 0, stream>>>(fc_w, fcb, 512 * 512);

    // ---- CSR build ----
    hipMemsetAsync(cnt, 0, (size_t)TOTKV * 4, stream);
    count_edges<<<cdiv(EE, 256), 256, 0, stream>>>(etype, dst, cnt);
    scan_blk<<<NBLK, 512, 0, stream>>>(cnt, offs, cntf, bsum);
    scan_top<<<1, 64, 0, stream>>>(bsum, boff, offs);
    scan_add<<<NBLK, 512, 0, stream>>>(offs, boff);
    hipMemcpyAsync(cursor, offs, (size_t)TOTKV * 4, hipMemcpyDeviceToDevice, stream);
    fill_edges<<<cdiv(EE, 256), 256, 0, stream>>>(etype, dst, src, cursor, srcs_s, dsts_s);
    graph_bounds<<<1, 128, 0, stream>>>(graph_ids, goff);

    pad2<<<cdiv(NP * 64, 256), 256, 0, stream>>>(in_feat, hbfA);

    const ushort* win = wihb + (size_t)1024 * 512;   // n-gate rows of w_ih
    const ushort* whn = whhb + (size_t)1024 * 512;   // n-gate rows of w_hh

    ushort* hin = hbfA;
    ushort* hout = hbfB;
    for (int step = 0; step < NSTEPS; step++) {
        // step 0: h cols 256..511 are zero -> trim K on every GEMM touching h
        int ktMsgA = (step == 0) ? 256 : 512;     // per-segment K for msg gemms
        int ktMsg  = 2 * ktMsgA;
        int ktRZ   = (step == 0) ? 768 : 1024;    // abf(512) + h(256|512)
        int ktHN   = (step == 0) ? 256 : 512;
        // message passing: abf = sum_k S_k @ Wmsg_k^T + sum_k cnt_k*bmsg_k   (bf16)
        gather2<<<2 * NP / 4, 256, 0, stream>>>(offs, srcs_s, hin, S2, 0);
        gemm2<<<dim3(4, NP / 128), 256, 0, stream>>>(
            wmsgT, wmsgT + (size_t)1 * 262144, 512, S2, S2 + (size_t)NP * 512, ktMsgA, ktMsg,
            abf, 512, 0, nullptr, nullptr);
        gather2<<<2 * NP / 4, 256, 0, stream>>>(offs, srcs_s, hin, S2, 1);
        gemm2<<<dim3(4, NP / 128), 256, 0, stream>>>(
            wmsgT + (size_t)2 * 262144, wmsgT + (size_t)3 * 262144, 512, S2, S2 + (size_t)NP * 512, ktMsgA, ktMsg,
            abf, 512, 3, cntf, bmsg);
        // merged: rz = [abf|hin] @ Wrz^T -> S2 ; h_n = hin @ whn^T -> hout
        gemm_rzhn<<<dim3(12, NP / 128), 256, 0, stream>>>(
            wrz, whn, abf, hin, S2, hout, ktRZ, ktHN);
        // i_n GEMM + fused GRU epilogue -> hout = h_new
        gemm_gru<<<dim3(4, NP / 128), 256, 0, stream>>>(
            win, abf, S2, hin, b_ih, b_hh, hout);
        ushort* tmp = hin; hin = hout; hout = tmp;
    }
    // hin now holds final h (hbfA after 4 steps)

    norm_sig<<<NN, 64, 0, stream>>>(hin);
    // feat = h @ fc_w^T  (bf16) -> featbf (abf region)
    gemm2<<<dim3(4, NP / 128), 256, 0, stream>>>(
        fcb, fcb, 512, hin, hin, 512, 512, featbf, 512, 0, nullptr, nullptr);
    el_er2<<<NN, 64, 0, stream>>>(featbf, attn_l, attn_r, el, er);
    edge_scores<<<cdiv(EE, 256), 256, 0, stream>>>(srcs_s, dsts_s, el, er, esc);

    gat3<<<NN / 4, 256, 0, stream>>>(offs, srcs_s, esc, featbf, gat_bias, rst);
    hipMemsetAsync(hgm, 0, (size_t)GG * 512 * 4, stream);
    graph_mean2<<<dim3(GG, 8), 256, 0, stream>>>(rst, goff, hgm);
    classify<<<GG, 64, 0, stream>>>(hgm, goff, cw, cb, out);
}

// Round 13
// 1268.588 us; speedup vs baseline: 1.0236x; 1.0236x over previous
//
#include <hip/hip_runtime.h>
#include <math.h>

#define NN 20000
#define NP 20096           // NN padded to 128 (157 tiles)
#define EE 320000
#define GG 64
#define IN_F 256
#define NC 16
#define NSTEPS 4
#define KT 4
#define TOTKV (KT*NP)      // 80384 = 157 * 512
#define NBLK 157

typedef unsigned int uint;
typedef unsigned short ushort;
typedef __attribute__((ext_vector_type(2))) float f2;
typedef __attribute__((ext_vector_type(4))) float f4;
typedef __attribute__((ext_vector_type(4))) ushort u16x4;
typedef __attribute__((ext_vector_type(8))) ushort u16x8;
typedef __attribute__((ext_vector_type(8))) short s16x8;

#define GLD_LDS(gp, lp) __builtin_amdgcn_global_load_lds( \
    (const __attribute__((address_space(1))) void*)(gp),  \
    (__attribute__((address_space(3))) void*)(lp), 16, 0, 0)

__device__ __forceinline__ ushort f2b(float f) {
    uint u = __float_as_uint(f);
    u = (u + 0x7FFFu + ((u >> 16) & 1u)) >> 16;   // RNE f32->bf16
    return (ushort)u;
}
__device__ __forceinline__ float b2f(ushort s) { return __uint_as_float(((uint)s) << 16); }
__device__ __forceinline__ float sgm(float x) { return 1.f / (1.f + __expf(-x)); }
__device__ __forceinline__ float ftanh(float x) { return 2.f / (1.f + __expf(-2.f * x)) - 1.f; }

// XCD-aware work swizzle: all GX work-columns of a node-tile y land on one XCD
// (assumes flat-id % 8 round-robin). y rows >=152 (tail of 157) map linearly.
__device__ __forceinline__ void sw_xy(int GX, int& x, int& y) {
    int f = blockIdx.x + GX * blockIdx.y;
    int body = GX * 152;                 // 19 groups of 8 y-rows
    if (f < body) {
        int xcd = f & 7, j = f >> 3;
        x = j % GX;
        y = (j / GX) * 8 + xcd;
    } else {
        int r = f - body;
        x = r % GX;
        y = 152 + r / GX;
    }
}

// ---------- weight prep ----------
// WT[k][o][d] <- Wmsg[k][d][o], LDS-tiled 32x32 so both sides coalesce
__global__ void conv_msgT(const float* __restrict__ Wm, ushort* __restrict__ WT) {
    __shared__ ushort sh[32][33];
    int k = blockIdx.z;
    int d0 = blockIdx.x * 32, o0 = blockIdx.y * 32;
    int tx = threadIdx.x & 31, ty = threadIdx.x >> 5;   // ty 0..7
#pragma unroll
    for (int i = 0; i < 4; i++) {
        int d = d0 + ty + i * 8;
        sh[ty + i * 8][tx] = f2b(Wm[((size_t)k << 18) + (size_t)d * 512 + o0 + tx]);
    }
    __syncthreads();
#pragma unroll
    for (int i = 0; i < 4; i++) {
        int o = o0 + ty + i * 8;
        WT[((size_t)k << 18) + (size_t)o * 512 + d0 + tx] = sh[tx][ty + i * 8];
    }
}
__global__ void conv_copy(const float* __restrict__ x, ushort* __restrict__ y, int n) {
    int i = blockIdx.x * 256 + threadIdx.x;
    if (i < n) y[i] = f2b(x[i]);
}
// Wrz[o2][k2]: o2<512 -> r-gate rows, o2>=512 -> z-gate; k2<512 from w_ih, else w_hh
__global__ void build_wrz(const float* __restrict__ wih, const float* __restrict__ whh,
                          ushort* __restrict__ W) {
    int idx = blockIdx.x * 256 + threadIdx.x;
    if (idx >= 1024 * 1024) return;
    int o2 = idx >> 10, k2 = idx & 1023;
    int gate = o2 >> 9, o = o2 & 511;
    float v = (k2 < 512) ? wih[(gate * 512 + o) * 512 + k2]
                         : whh[(gate * 512 + o) * 512 + (k2 - 512)];
    W[idx] = f2b(v);
}

// ---------- CSR build (etype-major, dst-minor) ----------
__global__ void count_edges(const int* __restrict__ etype, const int* __restrict__ dst,
                            int* __restrict__ cnt) {
    int e = blockIdx.x * 256 + threadIdx.x;
    if (e >= EE) return;
    atomicAdd(&cnt[etype[e] * NP + dst[e]], 1);
}
__global__ __launch_bounds__(512) void scan_blk(const int* __restrict__ cnt,
                                                int* __restrict__ offs,
                                                float* __restrict__ cntf,
                                                int* __restrict__ bsum) {
    __shared__ int sh[512];
    int t = threadIdx.x, b = blockIdx.x;
    int i = b * 512 + t;
    int v = cnt[i];
    sh[t] = v; __syncthreads();
    for (int off = 1; off < 512; off <<= 1) {
        int add = (t >= off) ? sh[t - off] : 0;
        __syncthreads();
        sh[t] += add;
        __syncthreads();
    }
    offs[i] = sh[t] - v;         // local exclusive
    cntf[i] = (float)v;
    if (t == 511) bsum[b] = sh[511];
}
__global__ void scan_top(const int* __restrict__ bsum, int* __restrict__ boff,
                         int* __restrict__ offs) {
    if (threadIdx.x == 0) {
        int run = 0;
        for (int i = 0; i < NBLK; i++) { boff[i] = run; run += bsum[i]; }
        offs[TOTKV] = run;
    }
}
__global__ __launch_bounds__(512) void scan_add(int* __restrict__ offs,
                                                const int* __restrict__ boff) {
    int i = blockIdx.x * 512 + threadIdx.x;
    offs[i] += boff[blockIdx.x];
}
__global__ void fill_edges(const int* __restrict__ etype, const int* __restrict__ dst,
                           const int* __restrict__ src, int* __restrict__ cursor,
                           int* __restrict__ srcs_s, int* __restrict__ dsts_s) {
    int e = blockIdx.x * 256 + threadIdx.x;
    if (e >= EE) return;
    int pos = atomicAdd(&cursor[etype[e] * NP + dst[e]], 1);
    srcs_s[pos] = src[e];
    dsts_s[pos] = dst[e];
}

// ---------- pad input -> bf16 h (zeros for d>=256 and rows>=NN) ----------
__global__ void pad2(const float* __restrict__ in_feat, ushort* __restrict__ h) {
    int idx = blockIdx.x * 256 + threadIdx.x;   // one per 8 elems
    if (idx >= NP * 64) return;
    int n = idx >> 6, o = (idx & 63) * 8;
    u16x8 ov = {0,0,0,0,0,0,0,0};
    if (n < NN && o < IN_F) {
        f4 a = *(const f4*)(in_feat + (size_t)n * IN_F + o);
        f4 b = *(const f4*)(in_feat + (size_t)n * IN_F + o + 4);
        ov = (u16x8){ f2b(a[0]), f2b(a[1]), f2b(a[2]), f2b(a[3]),
                      f2b(b[0]), f2b(b[1]), f2b(b[2]), f2b(b[3]) };
    }
    *(u16x8*)(h + (size_t)n * 512 + o) = ov;
}

// ---------- gather for k-pair: S2[kl][v][:] = sum of hbf[src] over in-edges of etype kp*2+kl ----------
// half=1: only cols 0..255 are live in hin (step 0) -> process 4 cols/lane, half traffic
__global__ void gather2(const int* __restrict__ offs, const int* __restrict__ srcs,
                        const ushort* __restrict__ hin, ushort* __restrict__ S2, int kp,
                        int half) {
    int wv = threadIdx.x >> 6, lane = threadIdx.x & 63;
    int r = blockIdx.x * 4 + wv;                 // [0, 2*NP)
    int kl = (r >= NP) ? 1 : 0;
    int v = r - kl * NP;
    int k = kp * 2 + kl;
    int beg = offs[k * NP + v], end = offs[k * NP + v + 1];
    if (half) {
        float acc[4] = {0,0,0,0};
        for (int e = beg; e < end; e++) {
            int s = srcs[e];
            u16x4 hv = *(const u16x4*)(hin + (size_t)s * 512 + lane * 4);
#pragma unroll
            for (int j = 0; j < 4; j++) acc[j] += b2f(hv[j]);
        }
        u16x4 ov;
#pragma unroll
        for (int j = 0; j < 4; j++) ov[j] = f2b(acc[j]);
        *(u16x4*)(S2 + ((size_t)kl * NP + v) * 512 + lane * 4) = ov;
    } else {
        float acc[8] = {0,0,0,0,0,0,0,0};
        for (int e = beg; e < end; e++) {
            int s = srcs[e];
            u16x8 hv = *(const u16x8*)(hin + (size_t)s * 512 + lane * 8);
#pragma unroll
            for (int j = 0; j < 8; j++) acc[j] += b2f(hv[j]);
        }
        u16x8 ov;
#pragma unroll
        for (int j = 0; j < 8; j++) ov[j] = f2b(acc[j]);
        *(u16x8*)(S2 + ((size_t)kl * NP + v) * 512 + lane * 8) = ov;
    }
}

// ---------- shared MFMA GEMM body: 128x128 tile, global_load_lds + XOR swizzle ----------
// C[node][o] = sum_k B[node][k] * W[o][k], K split at KtA between (Wa,Ba) and (Wb,Bb).
// B matrices stride 512. flags: 1 = accumulate bf16 C; 2 = add sum_k cntf*bmsg
__device__ __forceinline__ void gemm_body(
    ushort* As, ushort* Bs,
    const ushort* __restrict__ Wa, const ushort* __restrict__ Wb, int swA,
    const ushort* __restrict__ Ba, const ushort* __restrict__ Bb,
    int KtA, int Kt, ushort* __restrict__ C, int ldC, int o0, int n0, int flags,
    const float* __restrict__ cntf, const float* __restrict__ bmsg) {
    int t = threadIdx.x;
    int wave = t >> 6, lane = t & 63;
    int wm = wave & 1, wn = wave >> 1;
    int l16 = lane & 15, quad = lane >> 4;
    f4 acc[4][4];
#pragma unroll
    for (int i = 0; i < 4; i++)
#pragma unroll
        for (int j = 0; j < 4; j++) acc[i][j] = (f4){0,0,0,0};
    for (int kk = 0; kk < Kt; kk += 64) {
        const ushort* Wsrc = (kk < KtA) ? Wa : Wb;
        const ushort* Bsrc = (kk < KtA) ? Ba : Bb;
        int ko = (kk < KtA) ? kk : kk - KtA;
#pragma unroll
        for (int i = 0; i < 4; i++) {
            int c = i * 256 + t;                  // LDS 16B slot id, 0..1023
            int row = c >> 3, pc = c & 7;         // physical chunk pc
            int gcol = ((pc ^ (row & 7)) << 3);   // XOR swizzle: source logical chunk
            int ldsoff = (i * 256 + wave * 64) * 8;   // wave-uniform, lane*16B added by HW
            GLD_LDS(Wsrc + (size_t)(o0 + row) * swA + ko + gcol, As + ldsoff);
            GLD_LDS(Bsrc + (size_t)(n0 + row) * 512 + ko + gcol, Bs + ldsoff);
        }
        __syncthreads();
#pragma unroll
        for (int ks = 0; ks < 64; ks += 32) {
            s16x8 af[4], bf[4];
            int j = (ks >> 3) + quad;             // logical chunk
#pragma unroll
            for (int mi = 0; mi < 4; mi++) {
                int R = wm*64 + mi*16 + l16;
                af[mi] = *(const s16x8*)&As[R * 64 + ((j ^ (R & 7)) << 3)];
            }
#pragma unroll
            for (int ni = 0; ni < 4; ni++) {
                int R = wn*64 + ni*16 + l16;
                bf[ni] = *(const s16x8*)&Bs[R * 64 + ((j ^ (R & 7)) << 3)];
            }
#pragma unroll
            for (int mi = 0; mi < 4; mi++)
#pragma unroll
                for (int ni = 0; ni < 4; ni++)
                    acc[mi][ni] = __builtin_amdgcn_mfma_f32_16x16x32_bf16(af[mi], bf[ni], acc[mi][ni], 0, 0, 0);
        }
        __syncthreads();
    }
#pragma unroll
    for (int ni = 0; ni < 4; ni++) {
        int node = n0 + wn*64 + ni*16 + l16;
#pragma unroll
        for (int mi = 0; mi < 4; mi++) {
            int o = o0 + wm*64 + mi*16 + quad*4;
            f4 v = acc[mi][ni];
            if (flags & 2) {
#pragma unroll
                for (int k = 0; k < KT; k++) {
                    float ck = cntf[k * NP + node];
                    f4 bm = *(const f4*)(bmsg + k * 512 + o);
                    v += ck * bm;
                }
            }
            ushort* cp = C + (size_t)node * ldC + o;
            if (flags & 1) {
                u16x4 old = *(const u16x4*)cp;
                v += (f4){ b2f(old[0]), b2f(old[1]), b2f(old[2]), b2f(old[3]) };
            }
            u16x4 ov = { f2b(v[0]), f2b(v[1]), f2b(v[2]), f2b(v[3]) };
            *(u16x4*)cp = ov;
        }
    }
}

// grid: x = output chunk, y = node tile (XCD-swizzled)
__global__ __launch_bounds__(256, 3) void gemm2(
    const ushort* Wa, const ushort* Wb, int swA,
    const ushort* Ba, const ushort* Bb, int KtA, int Kt,
    ushort* C, int ldC, int flags,
    const float* cntf, const float* bmsg) {
    __shared__ ushort As[128 * 64];
    __shared__ ushort Bs[128 * 64];
    int x, y; sw_xy(gridDim.x, x, y);
    gemm_body(As, Bs, Wa, Wb, swA, Ba, Bb, KtA, Kt, C, ldC,
              x * 128, y * 128, flags, cntf, bmsg);
}

// merged rz + hn dispatch: x<8 -> rz (M=1024), x>=8 -> hn (M=512)
__global__ __launch_bounds__(256, 3) void gemm_rzhn(
    const ushort* wrz, const ushort* whn,
    const ushort* abf, const ushort* hin,
    ushort* rzout, ushort* hnout, int ktRZ, int ktHN) {
    __shared__ ushort As[128 * 64];
    __shared__ ushort Bs[128 * 64];
    int x, y; sw_xy(gridDim.x, x, y);
    if (x < 8) {
        gemm_body(As, Bs, wrz, wrz + 512, 1024, abf, hin, 512, ktRZ,
                  rzout, 1024, x * 128, y * 128, 0, nullptr, nullptr);
    } else {
        gemm_body(As, Bs, whn, whn, 512, hin, hin, 512, ktHN,
                  hnout, 512, (x - 8) * 128, y * 128, 0, nullptr, nullptr);
    }
}

// ---------- i_n GEMM with fused GRU epilogue ----------
__global__ __launch_bounds__(256, 3) void gemm_gru(
    const ushort* __restrict__ W, const ushort* __restrict__ Bm,
    const ushort* __restrict__ rz, const ushort* __restrict__ hin,
    const float* __restrict__ b_ih, const float* __restrict__ b_hh,
    ushort* __restrict__ hnb) {
    __shared__ ushort As[128 * 64];
    __shared__ ushort Bs[128 * 64];
    int t = threadIdx.x;
    int x, y; sw_xy(gridDim.x, x, y);
    int o0 = x * 128, n0 = y * 128;
    int wave = t >> 6, lane = t & 63;
    int wm = wave & 1, wn = wave >> 1;
    int l16 = lane & 15, quad = lane >> 4;
    f4 acc[4][4];
#pragma unroll
    for (int i = 0; i < 4; i++)
#pragma unroll
        for (int j = 0; j < 4; j++) acc[i][j] = (f4){0,0,0,0};
    for (int kk = 0; kk < 512; kk += 64) {
#pragma unroll
        for (int i = 0; i < 4; i++) {
            int c = i * 256 + t;
            int row = c >> 3, pc = c & 7;
            int gcol = ((pc ^ (row & 7)) << 3);
            int ldsoff = (i * 256 + wave * 64) * 8;
            GLD_LDS(W + (size_t)(o0 + row) * 512 + kk + gcol, As + ldsoff);
            GLD_LDS(Bm + (size_t)(n0 + row) * 512 + kk + gcol, Bs + ldsoff);
        }
        __syncthreads();
#pragma unroll
        for (int ks = 0; ks < 64; ks += 32) {
            s16x8 af[4], bf[4];
            int j = (ks >> 3) + quad;
#pragma unroll
            for (int mi = 0; mi < 4; mi++) {
                int R = wm*64 + mi*16 + l16;
                af[mi] = *(const s16x8*)&As[R * 64 + ((j ^ (R & 7)) << 3)];
            }
#pragma unroll
            for (int ni = 0; ni < 4; ni++) {
                int R = wn*64 + ni*16 + l16;
                bf[ni] = *(const s16x8*)&Bs[R * 64 + ((j ^ (R & 7)) << 3)];
            }
#pragma unroll
            for (int mi = 0; mi < 4; mi++)
#pragma unroll
                for (int ni = 0; ni < 4; ni++)
                    acc[mi][ni] = __builtin_amdgcn_mfma_f32_16x16x32_bf16(af[mi], bf[ni], acc[mi][ni], 0, 0, 0);
        }
        __syncthreads();
    }
#pragma unroll
    for (int ni = 0; ni < 4; ni++) {
        int node = n0 + wn*64 + ni*16 + l16;
#pragma unroll
        for (int mi = 0; mi < 4; mi++) {
            int o = o0 + wm*64 + mi*16 + quad*4;
            u16x4 rz1 = *(const u16x4*)(rz + (size_t)node * 1024 + o);
            u16x4 rz2 = *(const u16x4*)(rz + (size_t)node * 1024 + 512 + o);
            u16x4 hnv = *(const u16x4*)(hnb + (size_t)node * 512 + o);
            u16x4 hol = *(const u16x4*)(hin + (size_t)node * 512 + o);
            f4 bi0 = *(const f4*)(b_ih + o);
            f4 bi1 = *(const f4*)(b_ih + 512 + o);
            f4 bi2 = *(const f4*)(b_ih + 1024 + o);
            f4 bh0 = *(const f4*)(b_hh + o);
            f4 bh1 = *(const f4*)(b_hh + 512 + o);
            f4 bh2 = *(const f4*)(b_hh + 1024 + o);
            u16x4 ov;
#pragma unroll
            for (int r = 0; r < 4; r++) {
                float rg = sgm(b2f(rz1[r]) + bi0[r] + bh0[r]);
                float zg = sgm(b2f(rz2[r]) + bi1[r] + bh1[r]);
                float nv = ftanh(acc[mi][ni][r] + bi2[r] + rg * (b2f(hnv[r]) + bh2[r]));
                ov[r] = f2b((1.f - zg) * nv + zg * b2f(hol[r]));
            }
            *(u16x4*)(hnb + (size_t)node * 512 + o) = ov;
        }
    }
}

// ---------- L2 normalize + sigmoid (bf16 in/out), one wave per node ----------
__global__ void norm_sig(ushort* __restrict__ h) {
    int n = blockIdx.x, lane = threadIdx.x;   // 64 threads
    u16x8 v = *(const u16x8*)(h + (size_t)n * 512 + lane * 8);
    float f[8], ss = 0.f;
#pragma unroll
    for (int j = 0; j < 8; j++) { f[j] = b2f(v[j]); ss += f[j] * f[j]; }
    for (int off = 32; off > 0; off >>= 1) ss += __shfl_xor(ss, off);
    float inv = 1.f / fmaxf(sqrtf(ss), 1e-12f);
    u16x8 ov;
#pragma unroll
    for (int j = 0; j < 8; j++) ov[j] = f2b(sgm(f[j] * inv));
    *(u16x8*)(h + (size_t)n * 512 + lane * 8) = ov;
}

// ---------- el/er from bf16 feat, one wave per node ----------
__global__ void el_er2(const ushort* __restrict__ feat, const float* __restrict__ attn_l,
                       const float* __restrict__ attn_r, float* __restrict__ el,
                       float* __restrict__ er) {
    int n = blockIdx.x, lane = threadIdx.x;   // 64
    int head = lane >> 5;
    int ld = (lane * 8) & 255;
    u16x8 v = *(const u16x8*)(feat + (size_t)n * 512 + lane * 8);
    float sl = 0.f, sr = 0.f;
#pragma unroll
    for (int j = 0; j < 8; j++) {
        float f = b2f(v[j]);
        sl += f * attn_l[head * 256 + ld + j];
        sr += f * attn_r[head * 256 + ld + j];
    }
    for (int off = 16; off > 0; off >>= 1) { sl += __shfl_xor(sl, off); sr += __shfl_xor(sr, off); }
    if ((lane & 31) == 0) { el[n * 2 + head] = sl; er[n * 2 + head] = sr; }
}

// ---------- per-CSR-slot edge scores (leaky relu), both heads ----------
__global__ void edge_scores(const int* __restrict__ srcs, const int* __restrict__ dsts,
                            const float* __restrict__ el, const float* __restrict__ er,
                            float* __restrict__ esc) {
    int e = blockIdx.x * 256 + threadIdx.x;
    if (e >= EE) return;
    int s = srcs[e], d = dsts[e];
    f2 elv = *(const f2*)(el + (size_t)s * 2);
    f2 erv = *(const f2*)(er + (size_t)d * 2);
    float s0 = elv[0] + erv[0]; s0 = s0 < 0.f ? 0.2f * s0 : s0;
    float s1 = elv[1] + erv[1]; s1 = s1 < 0.f ? 0.2f * s1 : s1;
    *(f2*)(esc + (size_t)e * 2) = (f2){ s0, s1 };
}

// ---------- fused GAT: softmax over in-edges + aggregation + bias/relu, rst f32 out (no atomics) ----------
__global__ void gat3(const int* __restrict__ offs, const int* __restrict__ srcs,
                     const float* __restrict__ esc, const ushort* __restrict__ feat,
                     const float* __restrict__ gat_bias, float* __restrict__ rst) {
    int wave = threadIdx.x >> 6, lane = threadIdx.x & 63;
    int v = blockIdx.x * 4 + wave;
    int beg[KT], end[KT];
#pragma unroll
    for (int k = 0; k < KT; k++) { beg[k] = offs[k * NP + v]; end[k] = offs[k * NP + v + 1]; }
    float m0 = -1e30f, m1 = -1e30f;
#pragma unroll
    for (int k = 0; k < KT; k++)
        for (int base = beg[k]; base < end[k]; base += 64) {
            int e = base + lane;
            if (e < end[k]) {
                f2 s = *(const f2*)(esc + (size_t)e * 2);
                m0 = fmaxf(m0, s[0]); m1 = fmaxf(m1, s[1]);
            }
        }
    for (int off = 32; off > 0; off >>= 1) {
        m0 = fmaxf(m0, __shfl_xor(m0, off));
        m1 = fmaxf(m1, __shfl_xor(m1, off));
    }
    float d0 = 0.f, d1 = 0.f;
#pragma unroll
    for (int k = 0; k < KT; k++)
        for (int base = beg[k]; base < end[k]; base += 64) {
            int e = base + lane;
            if (e < end[k]) {
                f2 s = *(const f2*)(esc + (size_t)e * 2);
                d0 += __expf(s[0] - m0); d1 += __expf(s[1] - m1);
            }
        }
    for (int off = 32; off > 0; off >>= 1) { d0 += __shfl_xor(d0, off); d1 += __shfl_xor(d1, off); }
    int head = lane >> 5;
    float mm = head ? m1 : m0;
    float iv = head ? (d1 > 0.f ? 1.f / d1 : 0.f) : (d0 > 0.f ? 1.f / d0 : 0.f);
    float acc[8] = {0,0,0,0,0,0,0,0};
#pragma unroll
    for (int k = 0; k < KT; k++)
        for (int e = beg[k]; e < end[k]; e++) {
            float sc = esc[(size_t)e * 2 + head];
            float al = __expf(sc - mm) * iv;
            u16x8 fv = *(const u16x8*)(feat + (size_t)srcs[e] * 512 + lane * 8);
#pragma unroll
            for (int j = 0; j < 8; j++) acc[j] += al * b2f(fv[j]);
        }
    int di = lane * 8;
    f4 o0, o1;
#pragma unroll
    for (int j = 0; j < 4; j++) {
        o0[j] = fmaxf(acc[j] + gat_bias[di + j], 0.f);
        o1[j] = fmaxf(acc[4 + j] + gat_bias[di + 4 + j], 0.f);
    }
    *(f4*)(rst + (size_t)v * 512 + di) = o0;
    *(f4*)(rst + (size_t)v * 512 + di + 4) = o1;
}

// ---------- graph boundaries via binary search on sorted graph_ids ----------
__global__ void graph_bounds(const int* __restrict__ gids, int* __restrict__ goff) {
    int g = threadIdx.x;   // 128 threads, need 0..64
    if (g > GG) return;
    int lo = 0, hi = NN;
    while (lo < hi) { int mid = (lo + hi) >> 1; if (gids[mid] < g) lo = mid + 1; else hi = mid; }
    goff[g] = lo;
}

// ---------- per-graph partial sums of rst -> hgm (atomic, 8 chunks/graph) ----------
__global__ void graph_mean2(const float* __restrict__ rst, const int* __restrict__ goff,
                            float* __restrict__ hgm) {
    int g = blockIdx.x, yc = blockIdx.y, t = threadIdx.x;
    int beg = goff[g], end = goff[g + 1];
    float s0 = 0.f, s1 = 0.f;
    for (int n = beg + yc; n < end; n += 8) {
        s0 += rst[(size_t)n * 512 + t];
        s1 += rst[(size_t)n * 512 + 256 + t];
    }
    atomicAdd(&hgm[g * 512 + t], s0);
    atomicAdd(&hgm[g * 512 + 256 + t], s1);
}

// ---------- classify (divides by graph size) ----------
__global__ void classify(const float* __restrict__ hgm, const int* __restrict__ goff,
                         const float* __restrict__ cw, const float* __restrict__ cb,
                         float* __restrict__ out) {
    __shared__ float hl[512];
    int g = blockIdx.x, t = threadIdx.x;  // 64 threads
    int cntn = goff[g + 1] - goff[g];
    float inv = (cntn > 0) ? 1.f / (float)cntn : 0.f;
    for (int d = t; d < 512; d += 64) hl[d] = hgm[g * 512 + d] * inv;
    __syncthreads();
    if (t < 32) {
        int hd = t >> 4, c = t & 15;
        float acc = 0.f;
        for (int d = 0; d < 256; d++) acc += hl[hd * 256 + d] * cw[c * 256 + d];
        out[(g * 2 + hd) * NC + c] = acc + cb[c];
    }
}

static inline int cdiv(int a, int b) { return (a + b - 1) / b; }
static inline size_t alup(size_t x) { return (x + 255) & ~(size_t)255; }

extern "C" void kernel_launch(void* const* d_in, const int* in_sizes, int n_in,
                              void* d_out, int out_size, void* d_ws, size_t ws_size,
                              hipStream_t stream) {
    const float* in_feat   = (const float*)d_in[0];
    const int*   src       = (const int*)d_in[1];
    const int*   dst       = (const int*)d_in[2];
    const int*   etype     = (const int*)d_in[3];
    const int*   graph_ids = (const int*)d_in[4];
    const float* Wmsg      = (const float*)d_in[5];
    const float* bmsg      = (const float*)d_in[6];
    const float* w_ih      = (const float*)d_in[7];
    const float* w_hh      = (const float*)d_in[8];
    const float* b_ih      = (const float*)d_in[9];
    const float* b_hh      = (const float*)d_in[10];
    const float* fc_w      = (const float*)d_in[11];
    const float* attn_l    = (const float*)d_in[12];
    const float* attn_r    = (const float*)d_in[13];
    const float* gat_bias  = (const float*)d_in[14];
    const float* cw        = (const float*)d_in[15];
    const float* cb        = (const float*)d_in[16];
    float* out = (float*)d_out;

    char* p = (char*)d_ws;
    ushort* hbfA  = (ushort*)p; p += alup((size_t)NP * 512 * 2);
    ushort* hbfB  = (ushort*)p; p += alup((size_t)NP * 512 * 2);
    ushort* abf   = (ushort*)p; p += alup((size_t)NP * 512 * 2);
    ushort* S2    = (ushort*)p; p += alup((size_t)2 * NP * 512 * 2);  // gathered S pair / rz (NP x 1024) / rst f32
    ushort* wmsgT = (ushort*)p; p += alup((size_t)KT * 512 * 512 * 2);
    ushort* wihb  = (ushort*)p; p += alup((size_t)1536 * 512 * 2);
    ushort* whhb  = (ushort*)p; p += alup((size_t)1536 * 512 * 2);
    ushort* wrz   = (ushort*)p; p += alup((size_t)1024 * 1024 * 2);
    ushort* fcb   = (ushort*)p; p += alup((size_t)512 * 512 * 2);
    int*    cnt   = (int*)p;    p += alup((size_t)TOTKV * 4);
    int*    offs  = (int*)p;    p += alup(((size_t)TOTKV + 1) * 4);
    int*    cursor= (int*)p;    p += alup(((size_t)TOTKV + 1) * 4);
    float*  cntf  = (float*)p;  p += alup((size_t)TOTKV * 4);
    int*    bsum  = (int*)p;    p += alup((size_t)NBLK * 4);
    int*    boff  = (int*)p;    p += alup((size_t)NBLK * 4);
    int*    srcs_s= (int*)p;    p += alup((size_t)EE * 4);
    int*    dsts_s= (int*)p;    p += alup((size_t)EE * 4);
    float*  esc   = (float*)p;  p += alup((size_t)EE * 2 * 4);
    float*  el    = (float*)p;  p += alup((size_t)NN * 2 * 4);
    float*  er    = (float*)p;  p += alup((size_t)NN * 2 * 4);
    int*    goff  = (int*)p;    p += alup((size_t)(GG + 1) * 4);
    float*  hgm   = (float*)p;  p += alup((size_t)GG * 512 * 4);
    ushort* featbf = abf;          // alias: abf free after last gemm_gru
    float*  rst    = (float*)S2;   // alias: rz region free after last gemm_gru (same byte size)

    // ---- weight prep ----
    conv_msgT<<<dim3(16, 16, 4), 256, 0, stream>>>(Wmsg, wmsgT);
    conv_copy<<<cdiv(1536 * 512, 256), 256, 0, stream>>>(w_ih, wihb, 1536 * 512);
    conv_copy<<<cdiv(1536 * 512, 256), 256, 0, stream>>>(w_hh, whhb, 1536 * 512);
    build_wrz<<<cdiv(1024 * 1024, 256), 256, 0, stream>>>(w_ih, w_hh, wrz);
    conv_copy<<<cdiv(512 * 512, 256), 256, 0, stream>>>(fc_w, fcb, 512 * 512);

    // ---- CSR build ----
    hipMemsetAsync(cnt, 0, (size_t)TOTKV * 4, stream);
    count_edges<<<cdiv(EE, 256), 256, 0, stream>>>(etype, dst, cnt);
    scan_blk<<<NBLK, 512, 0, stream>>>(cnt, offs, cntf, bsum);
    scan_top<<<1, 64, 0, stream>>>(bsum, boff, offs);
    scan_add<<<NBLK, 512, 0, stream>>>(offs, boff);
    hipMemcpyAsync(cursor, offs, (size_t)TOTKV * 4, hipMemcpyDeviceToDevice, stream);
    fill_edges<<<cdiv(EE, 256), 256, 0, stream>>>(etype, dst, src, cursor, srcs_s, dsts_s);
    graph_bounds<<<1, 128, 0, stream>>>(graph_ids, goff);

    pad2<<<cdiv(NP * 64, 256), 256, 0, stream>>>(in_feat, hbfA);

    const ushort* win = wihb + (size_t)1024 * 512;   // n-gate rows of w_ih
    const ushort* whn = whhb + (size_t)1024 * 512;   // n-gate rows of w_hh

    ushort* hin = hbfA;
    ushort* hout = hbfB;
    for (int step = 0; step < NSTEPS; step++) {
        // step 0: h cols 256..511 are zero -> trim K on every GEMM touching h
        int half   = (step == 0) ? 1 : 0;
        int ktMsgA = (step == 0) ? 256 : 512;     // per-segment K for msg gemms
        int ktMsg  = 2 * ktMsgA;
        int ktRZ   = (step == 0) ? 768 : 1024;    // abf(512) + h(256|512)
        int ktHN   = (step == 0) ? 256 : 512;
        // message passing: abf = sum_k S_k @ Wmsg_k^T + sum_k cnt_k*bmsg_k   (bf16)
        gather2<<<2 * NP / 4, 256, 0, stream>>>(offs, srcs_s, hin, S2, 0, half);
        gemm2<<<dim3(4, NP / 128), 256, 0, stream>>>(
            wmsgT, wmsgT + (size_t)1 * 262144, 512, S2, S2 + (size_t)NP * 512, ktMsgA, ktMsg,
            abf, 512, 0, nullptr, nullptr);
        gather2<<<2 * NP / 4, 256, 0, stream>>>(offs, srcs_s, hin, S2, 1, half);
        gemm2<<<dim3(4, NP / 128), 256, 0, stream>>>(
            wmsgT + (size_t)2 * 262144, wmsgT + (size_t)3 * 262144, 512, S2, S2 + (size_t)NP * 512, ktMsgA, ktMsg,
            abf, 512, 3, cntf, bmsg);
        // merged: rz = [abf|hin] @ Wrz^T -> S2 ; h_n = hin @ whn^T -> hout
        gemm_rzhn<<<dim3(12, NP / 128), 256, 0, stream>>>(
            wrz, whn, abf, hin, S2, hout, ktRZ, ktHN);
        // i_n GEMM + fused GRU epilogue -> hout = h_new
        gemm_gru<<<dim3(4, NP / 128), 256, 0, stream>>>(
            win, abf, S2, hin, b_ih, b_hh, hout);
        ushort* tmp = hin; hin = hout; hout = tmp;
    }
    // hin now holds final h (hbfA after 4 steps)

    norm_sig<<<NN, 64, 0, stream>>>(hin);
    // feat = h @ fc_w^T  (bf16) -> featbf (abf region)
    gemm2<<<dim3(4, NP / 128), 256, 0, stream>>>(
        fcb, fcb, 512, hin, hin, 512, 512, featbf, 512, 0, nullptr, nullptr);
    el_er2<<<NN, 64, 0, stream>>>(featbf, attn_l, attn_r, el, er);
    edge_scores<<<cdiv(EE, 256), 256, 0, stream>>>(srcs_s, dsts_s, el, er, esc);

    gat3<<<NN / 4, 256, 0, stream>>>(offs, srcs_s, esc, featbf, gat_bias, rst);
    hipMemsetAsync(hgm, 0, (size_t)GG * 512 * 4, stream);
    graph_mean2<<<dim3(GG, 8), 256, 0, stream>>>(rst, goff, hgm);
    classify<<<GG, 64, 0, stream>>>(hgm, goff, cw, cb, out);
}

// Round 14
// 1217.166 us; speedup vs baseline: 1.0669x; 1.0422x over previous
//
#include <hip/hip_runtime.h>
#include <math.h>

#define NN 20000
#define NP 20096           // NN padded to 128 (157 tiles)
#define EE 320000
#define GG 64
#define IN_F 256
#define NC 16
#define NSTEPS 4
#define KT 4
#define TOTKV (KT*NP)      // 80384 = 157 * 512
#define NBLK 157

typedef unsigned int uint;
typedef unsigned short ushort;
typedef __attribute__((ext_vector_type(2))) float f2;
typedef __attribute__((ext_vector_type(4))) float f4;
typedef __attribute__((ext_vector_type(4))) ushort u16x4;
typedef __attribute__((ext_vector_type(8))) ushort u16x8;
typedef __attribute__((ext_vector_type(8))) short s16x8;

#define GLD_LDS(gp, lp) __builtin_amdgcn_global_load_lds( \
    (const __attribute__((address_space(1))) void*)(gp),  \
    (__attribute__((address_space(3))) void*)(lp), 16, 0, 0)

__device__ __forceinline__ ushort f2b(float f) {
    uint u = __float_as_uint(f);
    u = (u + 0x7FFFu + ((u >> 16) & 1u)) >> 16;   // RNE f32->bf16
    return (ushort)u;
}
__device__ __forceinline__ float b2f(ushort s) { return __uint_as_float(((uint)s) << 16); }
__device__ __forceinline__ float sgm(float x) { return 1.f / (1.f + __expf(-x)); }
__device__ __forceinline__ float ftanh(float x) { return 2.f / (1.f + __expf(-2.f * x)) - 1.f; }

// XCD-aware work swizzle: all GX work-columns of a node-tile y land on one XCD
// (assumes flat-id % 8 round-robin). y rows >=152 (tail of 157) map linearly.
__device__ __forceinline__ void sw_xy(int GX, int& x, int& y) {
    int f = blockIdx.x + GX * blockIdx.y;
    int body = GX * 152;                 // 19 groups of 8 y-rows
    if (f < body) {
        int xcd = f & 7, j = f >> 3;
        x = j % GX;
        y = (j / GX) * 8 + xcd;
    } else {
        int r = f - body;
        x = r % GX;
        y = 152 + r / GX;
    }
}

// ---------- weight prep ----------
// WT[k][o][d] <- Wmsg[k][d][o], LDS-tiled 32x32 so both sides coalesce
__global__ void conv_msgT(const float* __restrict__ Wm, ushort* __restrict__ WT) {
    __shared__ ushort sh[32][33];
    int k = blockIdx.z;
    int d0 = blockIdx.x * 32, o0 = blockIdx.y * 32;
    int tx = threadIdx.x & 31, ty = threadIdx.x >> 5;   // ty 0..7
#pragma unroll
    for (int i = 0; i < 4; i++) {
        int d = d0 + ty + i * 8;
        sh[ty + i * 8][tx] = f2b(Wm[((size_t)k << 18) + (size_t)d * 512 + o0 + tx]);
    }
    __syncthreads();
#pragma unroll
    for (int i = 0; i < 4; i++) {
        int o = o0 + ty + i * 8;
        WT[((size_t)k << 18) + (size_t)o * 512 + d0 + tx] = sh[tx][ty + i * 8];
    }
}
__global__ void conv_copy(const float* __restrict__ x, ushort* __restrict__ y, int n) {
    int i = blockIdx.x * 256 + threadIdx.x;
    if (i < n) y[i] = f2b(x[i]);
}
// Wrz[o2][k2]: o2<512 -> r-gate rows, o2>=512 -> z-gate; k2<512 from w_ih, else w_hh
__global__ void build_wrz(const float* __restrict__ wih, const float* __restrict__ whh,
                          ushort* __restrict__ W) {
    int idx = blockIdx.x * 256 + threadIdx.x;
    if (idx >= 1024 * 1024) return;
    int o2 = idx >> 10, k2 = idx & 1023;
    int gate = o2 >> 9, o = o2 & 511;
    float v = (k2 < 512) ? wih[(gate * 512 + o) * 512 + k2]
                         : whh[(gate * 512 + o) * 512 + (k2 - 512)];
    W[idx] = f2b(v);
}

// ---------- CSR build (etype-major, dst-minor) ----------
__global__ void count_edges(const int* __restrict__ etype, const int* __restrict__ dst,
                            int* __restrict__ cnt) {
    int e = blockIdx.x * 256 + threadIdx.x;
    if (e >= EE) return;
    atomicAdd(&cnt[etype[e] * NP + dst[e]], 1);
}
__global__ __launch_bounds__(512) void scan_blk(const int* __restrict__ cnt,
                                                int* __restrict__ offs,
                                                float* __restrict__ cntf,
                                                int* __restrict__ bsum) {
    __shared__ int sh[512];
    int t = threadIdx.x, b = blockIdx.x;
    int i = b * 512 + t;
    int v = cnt[i];
    sh[t] = v; __syncthreads();
    for (int off = 1; off < 512; off <<= 1) {
        int add = (t >= off) ? sh[t - off] : 0;
        __syncthreads();
        sh[t] += add;
        __syncthreads();
    }
    offs[i] = sh[t] - v;         // local exclusive
    cntf[i] = (float)v;
    if (t == 511) bsum[b] = sh[511];
}
__global__ void scan_top(const int* __restrict__ bsum, int* __restrict__ boff,
                         int* __restrict__ offs) {
    if (threadIdx.x == 0) {
        int run = 0;
        for (int i = 0; i < NBLK; i++) { boff[i] = run; run += bsum[i]; }
        offs[TOTKV] = run;
    }
}
__global__ __launch_bounds__(512) void scan_add(int* __restrict__ offs,
                                                const int* __restrict__ boff) {
    int i = blockIdx.x * 512 + threadIdx.x;
    offs[i] += boff[blockIdx.x];
}
__global__ void fill_edges(const int* __restrict__ etype, const int* __restrict__ dst,
                           const int* __restrict__ src, int* __restrict__ cursor,
                           int* __restrict__ srcs_s, int* __restrict__ dsts_s) {
    int e = blockIdx.x * 256 + threadIdx.x;
    if (e >= EE) return;
    int pos = atomicAdd(&cursor[etype[e] * NP + dst[e]], 1);
    srcs_s[pos] = src[e];
    dsts_s[pos] = dst[e];
}

// ---------- pad input -> bf16 h (zeros for d>=256 and rows>=NN) ----------
__global__ void pad2(const float* __restrict__ in_feat, ushort* __restrict__ h) {
    int idx = blockIdx.x * 256 + threadIdx.x;   // one per 8 elems
    if (idx >= NP * 64) return;
    int n = idx >> 6, o = (idx & 63) * 8;
    u16x8 ov = {0,0,0,0,0,0,0,0};
    if (n < NN && o < IN_F) {
        f4 a = *(const f4*)(in_feat + (size_t)n * IN_F + o);
        f4 b = *(const f4*)(in_feat + (size_t)n * IN_F + o + 4);
        ov = (u16x8){ f2b(a[0]), f2b(a[1]), f2b(a[2]), f2b(a[3]),
                      f2b(b[0]), f2b(b[1]), f2b(b[2]), f2b(b[3]) };
    }
    *(u16x8*)(h + (size_t)n * 512 + o) = ov;
}

// ---------- gather for k-pair: S2[kl][v][:] = sum of hbf[src] over in-edges of etype kp*2+kl ----------
__global__ void gather2(const int* __restrict__ offs, const int* __restrict__ srcs,
                        const ushort* __restrict__ hin, ushort* __restrict__ S2, int kp) {
    int wv = threadIdx.x >> 6, lane = threadIdx.x & 63;
    int r = blockIdx.x * 4 + wv;                 // [0, 2*NP)
    int kl = (r >= NP) ? 1 : 0;
    int v = r - kl * NP;
    int k = kp * 2 + kl;
    int beg = offs[k * NP + v], end = offs[k * NP + v + 1];
    float acc[8] = {0,0,0,0,0,0,0,0};
    for (int e = beg; e < end; e++) {
        int s = srcs[e];
        u16x8 hv = *(const u16x8*)(hin + (size_t)s * 512 + lane * 8);
#pragma unroll
        for (int j = 0; j < 8; j++) acc[j] += b2f(hv[j]);
    }
    u16x8 ov;
#pragma unroll
    for (int j = 0; j < 8; j++) ov[j] = f2b(acc[j]);
    *(u16x8*)(S2 + ((size_t)kl * NP + v) * 512 + lane * 8) = ov;
}

// ---------- shared MFMA GEMM body: 128x128 tile, global_load_lds + XOR swizzle ----------
// C[node][o] = sum_k B[node][k] * W[o][k], K split at KtA between (Wa,Ba) and (Wb,Bb).
// B matrices stride 512. flags: 1 = accumulate bf16 C; 2 = add sum_k cntf*bmsg
__device__ __forceinline__ void gemm_body(
    ushort* As, ushort* Bs,
    const ushort* __restrict__ Wa, const ushort* __restrict__ Wb, int swA,
    const ushort* __restrict__ Ba, const ushort* __restrict__ Bb,
    int KtA, int Kt, ushort* __restrict__ C, int ldC, int o0, int n0, int flags,
    const float* __restrict__ cntf, const float* __restrict__ bmsg) {
    int t = threadIdx.x;
    int wave = t >> 6, lane = t & 63;
    int wm = wave & 1, wn = wave >> 1;
    int l16 = lane & 15, quad = lane >> 4;
    f4 acc[4][4];
#pragma unroll
    for (int i = 0; i < 4; i++)
#pragma unroll
        for (int j = 0; j < 4; j++) acc[i][j] = (f4){0,0,0,0};
    for (int kk = 0; kk < Kt; kk += 64) {
        const ushort* Wsrc = (kk < KtA) ? Wa : Wb;
        const ushort* Bsrc = (kk < KtA) ? Ba : Bb;
        int ko = (kk < KtA) ? kk : kk - KtA;
#pragma unroll
        for (int i = 0; i < 4; i++) {
            int c = i * 256 + t;                  // LDS 16B slot id, 0..1023
            int row = c >> 3, pc = c & 7;         // physical chunk pc
            int gcol = ((pc ^ (row & 7)) << 3);   // XOR swizzle: source logical chunk
            int ldsoff = (i * 256 + wave * 64) * 8;   // wave-uniform, lane*16B added by HW
            GLD_LDS(Wsrc + (size_t)(o0 + row) * swA + ko + gcol, As + ldsoff);
            GLD_LDS(Bsrc + (size_t)(n0 + row) * 512 + ko + gcol, Bs + ldsoff);
        }
        __syncthreads();
#pragma unroll
        for (int ks = 0; ks < 64; ks += 32) {
            s16x8 af[4], bf[4];
            int j = (ks >> 3) + quad;             // logical chunk
#pragma unroll
            for (int mi = 0; mi < 4; mi++) {
                int R = wm*64 + mi*16 + l16;
                af[mi] = *(const s16x8*)&As[R * 64 + ((j ^ (R & 7)) << 3)];
            }
#pragma unroll
            for (int ni = 0; ni < 4; ni++) {
                int R = wn*64 + ni*16 + l16;
                bf[ni] = *(const s16x8*)&Bs[R * 64 + ((j ^ (R & 7)) << 3)];
            }
#pragma unroll
            for (int mi = 0; mi < 4; mi++)
#pragma unroll
                for (int ni = 0; ni < 4; ni++)
                    acc[mi][ni] = __builtin_amdgcn_mfma_f32_16x16x32_bf16(af[mi], bf[ni], acc[mi][ni], 0, 0, 0);
        }
        __syncthreads();
    }
#pragma unroll
    for (int ni = 0; ni < 4; ni++) {
        int node = n0 + wn*64 + ni*16 + l16;
#pragma unroll
        for (int mi = 0; mi < 4; mi++) {
            int o = o0 + wm*64 + mi*16 + quad*4;
            f4 v = acc[mi][ni];
            if (flags & 2) {
#pragma unroll
                for (int k = 0; k < KT; k++) {
                    float ck = cntf[k * NP + node];
                    f4 bm = *(const f4*)(bmsg + k * 512 + o);
                    v += ck * bm;
                }
            }
            ushort* cp = C + (size_t)node * ldC + o;
            if (flags & 1) {
                u16x4 old = *(const u16x4*)cp;
                v += (f4){ b2f(old[0]), b2f(old[1]), b2f(old[2]), b2f(old[3]) };
            }
            u16x4 ov = { f2b(v[0]), f2b(v[1]), f2b(v[2]), f2b(v[3]) };
            *(u16x4*)cp = ov;
        }
    }
}

// grid: x = output chunk, y = node tile (XCD-swizzled)
__global__ __launch_bounds__(256, 3) void gemm2(
    const ushort* Wa, const ushort* Wb, int swA,
    const ushort* Ba, const ushort* Bb, int KtA, int Kt,
    ushort* C, int ldC, int flags,
    const float* cntf, const float* bmsg) {
    __shared__ ushort As[128 * 64];
    __shared__ ushort Bs[128 * 64];
    int x, y; sw_xy(gridDim.x, x, y);
    gemm_body(As, Bs, Wa, Wb, swA, Ba, Bb, KtA, Kt, C, ldC,
              x * 128, y * 128, flags, cntf, bmsg);
}

// merged rz + hn dispatch: x<8 -> rz (M=1024), x>=8 -> hn (M=512)
__global__ __launch_bounds__(256, 3) void gemm_rzhn(
    const ushort* wrz, const ushort* whn,
    const ushort* abf, const ushort* hin,
    ushort* rzout, ushort* hnout, int ktRZ, int ktHN) {
    __shared__ ushort As[128 * 64];
    __shared__ ushort Bs[128 * 64];
    int x, y; sw_xy(gridDim.x, x, y);
    if (x < 8) {
        gemm_body(As, Bs, wrz, wrz + 512, 1024, abf, hin, 512, ktRZ,
                  rzout, 1024, x * 128, y * 128, 0, nullptr, nullptr);
    } else {
        gemm_body(As, Bs, whn, whn, 512, hin, hin, 512, ktHN,
                  hnout, 512, (x - 8) * 128, y * 128, 0, nullptr, nullptr);
    }
}

// ---------- i_n GEMM with fused GRU epilogue ----------
__global__ __launch_bounds__(256, 3) void gemm_gru(
    const ushort* __restrict__ W, const ushort* __restrict__ Bm,
    const ushort* __restrict__ rz, const ushort* __restrict__ hin,
    const float* __restrict__ b_ih, const float* __restrict__ b_hh,
    ushort* __restrict__ hnb) {
    __shared__ ushort As[128 * 64];
    __shared__ ushort Bs[128 * 64];
    int t = threadIdx.x;
    int x, y; sw_xy(gridDim.x, x, y);
    int o0 = x * 128, n0 = y * 128;
    int wave = t >> 6, lane = t & 63;
    int wm = wave & 1, wn = wave >> 1;
    int l16 = lane & 15, quad = lane >> 4;
    f4 acc[4][4];
#pragma unroll
    for (int i = 0; i < 4; i++)
#pragma unroll
        for (int j = 0; j < 4; j++) acc[i][j] = (f4){0,0,0,0};
    for (int kk = 0; kk < 512; kk += 64) {
#pragma unroll
        for (int i = 0; i < 4; i++) {
            int c = i * 256 + t;
            int row = c >> 3, pc = c & 7;
            int gcol = ((pc ^ (row & 7)) << 3);
            int ldsoff = (i * 256 + wave * 64) * 8;
            GLD_LDS(W + (size_t)(o0 + row) * 512 + kk + gcol, As + ldsoff);
            GLD_LDS(Bm + (size_t)(n0 + row) * 512 + kk + gcol, Bs + ldsoff);
        }
        __syncthreads();
#pragma unroll
        for (int ks = 0; ks < 64; ks += 32) {
            s16x8 af[4], bf[4];
            int j = (ks >> 3) + quad;
#pragma unroll
            for (int mi = 0; mi < 4; mi++) {
                int R = wm*64 + mi*16 + l16;
                af[mi] = *(const s16x8*)&As[R * 64 + ((j ^ (R & 7)) << 3)];
            }
#pragma unroll
            for (int ni = 0; ni < 4; ni++) {
                int R = wn*64 + ni*16 + l16;
                bf[ni] = *(const s16x8*)&Bs[R * 64 + ((j ^ (R & 7)) << 3)];
            }
#pragma unroll
            for (int mi = 0; mi < 4; mi++)
#pragma unroll
                for (int ni = 0; ni < 4; ni++)
                    acc[mi][ni] = __builtin_amdgcn_mfma_f32_16x16x32_bf16(af[mi], bf[ni], acc[mi][ni], 0, 0, 0);
        }
        __syncthreads();
    }
#pragma unroll
    for (int ni = 0; ni < 4; ni++) {
        int node = n0 + wn*64 + ni*16 + l16;
#pragma unroll
        for (int mi = 0; mi < 4; mi++) {
            int o = o0 + wm*64 + mi*16 + quad*4;
            u16x4 rz1 = *(const u16x4*)(rz + (size_t)node * 1024 + o);
            u16x4 rz2 = *(const u16x4*)(rz + (size_t)node * 1024 + 512 + o);
            u16x4 hnv = *(const u16x4*)(hnb + (size_t)node * 512 + o);
            u16x4 hol = *(const u16x4*)(hin + (size_t)node * 512 + o);
            f4 bi0 = *(const f4*)(b_ih + o);
            f4 bi1 = *(const f4*)(b_ih + 512 + o);
            f4 bi2 = *(const f4*)(b_ih + 1024 + o);
            f4 bh0 = *(const f4*)(b_hh + o);
            f4 bh1 = *(const f4*)(b_hh + 512 + o);
            f4 bh2 = *(const f4*)(b_hh + 1024 + o);
            u16x4 ov;
#pragma unroll
            for (int r = 0; r < 4; r++) {
                float rg = sgm(b2f(rz1[r]) + bi0[r] + bh0[r]);
                float zg = sgm(b2f(rz2[r]) + bi1[r] + bh1[r]);
                float nv = ftanh(acc[mi][ni][r] + bi2[r] + rg * (b2f(hnv[r]) + bh2[r]));
                ov[r] = f2b((1.f - zg) * nv + zg * b2f(hol[r]));
            }
            *(u16x4*)(hnb + (size_t)node * 512 + o) = ov;
        }
    }
}

// ---------- L2 normalize + sigmoid (bf16 in/out), one wave per node ----------
__global__ void norm_sig(ushort* __restrict__ h) {
    int n = blockIdx.x, lane = threadIdx.x;   // 64 threads
    u16x8 v = *(const u16x8*)(h + (size_t)n * 512 + lane * 8);
    float f[8], ss = 0.f;
#pragma unroll
    for (int j = 0; j < 8; j++) { f[j] = b2f(v[j]); ss += f[j] * f[j]; }
    for (int off = 32; off > 0; off >>= 1) ss += __shfl_xor(ss, off);
    float inv = 1.f / fmaxf(sqrtf(ss), 1e-12f);
    u16x8 ov;
#pragma unroll
    for (int j = 0; j < 8; j++) ov[j] = f2b(sgm(f[j] * inv));
    *(u16x8*)(h + (size_t)n * 512 + lane * 8) = ov;
}

// ---------- el/er from bf16 feat, one wave per node ----------
__global__ void el_er2(const ushort* __restrict__ feat, const float* __restrict__ attn_l,
                       const float* __restrict__ attn_r, float* __restrict__ el,
                       float* __restrict__ er) {
    int n = blockIdx.x, lane = threadIdx.x;   // 64
    int head = lane >> 5;
    int ld = (lane * 8) & 255;
    u16x8 v = *(const u16x8*)(feat + (size_t)n * 512 + lane * 8);
    float sl = 0.f, sr = 0.f;
#pragma unroll
    for (int j = 0; j < 8; j++) {
        float f = b2f(v[j]);
        sl += f * attn_l[head * 256 + ld + j];
        sr += f * attn_r[head * 256 + ld + j];
    }
    for (int off = 16; off > 0; off >>= 1) { sl += __shfl_xor(sl, off); sr += __shfl_xor(sr, off); }
    if ((lane & 31) == 0) { el[n * 2 + head] = sl; er[n * 2 + head] = sr; }
}

// ---------- per-CSR-slot edge scores (leaky relu), both heads ----------
__global__ void edge_scores(const int* __restrict__ srcs, const int* __restrict__ dsts,
                            const float* __restrict__ el, const float* __restrict__ er,
                            float* __restrict__ esc) {
    int e = blockIdx.x * 256 + threadIdx.x;
    if (e >= EE) return;
    int s = srcs[e], d = dsts[e];
    f2 elv = *(const f2*)(el + (size_t)s * 2);
    f2 erv = *(const f2*)(er + (size_t)d * 2);
    float s0 = elv[0] + erv[0]; s0 = s0 < 0.f ? 0.2f * s0 : s0;
    float s1 = elv[1] + erv[1]; s1 = s1 < 0.f ? 0.2f * s1 : s1;
    *(f2*)(esc + (size_t)e * 2) = (f2){ s0, s1 };
}

// ---------- fused GAT: softmax over in-edges + aggregation + bias/relu, rst f32 out (no atomics) ----------
__global__ void gat3(const int* __restrict__ offs, const int* __restrict__ srcs,
                     const float* __restrict__ esc, const ushort* __restrict__ feat,
                     const float* __restrict__ gat_bias, float* __restrict__ rst) {
    int wave = threadIdx.x >> 6, lane = threadIdx.x & 63;
    int v = blockIdx.x * 4 + wave;
    int beg[KT], end[KT];
#pragma unroll
    for (int k = 0; k < KT; k++) { beg[k] = offs[k * NP + v]; end[k] = offs[k * NP + v + 1]; }
    float m0 = -1e30f, m1 = -1e30f;
#pragma unroll
    for (int k = 0; k < KT; k++)
        for (int base = beg[k]; base < end[k]; base += 64) {
            int e = base + lane;
            if (e < end[k]) {
                f2 s = *(const f2*)(esc + (size_t)e * 2);
                m0 = fmaxf(m0, s[0]); m1 = fmaxf(m1, s[1]);
            }
        }
    for (int off = 32; off > 0; off >>= 1) {
        m0 = fmaxf(m0, __shfl_xor(m0, off));
        m1 = fmaxf(m1, __shfl_xor(m1, off));
    }
    float d0 = 0.f, d1 = 0.f;
#pragma unroll
    for (int k = 0; k < KT; k++)
        for (int base = beg[k]; base < end[k]; base += 64) {
            int e = base + lane;
            if (e < end[k]) {
                f2 s = *(const f2*)(esc + (size_t)e * 2);
                d0 += __expf(s[0] - m0); d1 += __expf(s[1] - m1);
            }
        }
    for (int off = 32; off > 0; off >>= 1) { d0 += __shfl_xor(d0, off); d1 += __shfl_xor(d1, off); }
    int head = lane >> 5;
    float mm = head ? m1 : m0;
    float iv = head ? (d1 > 0.f ? 1.f / d1 : 0.f) : (d0 > 0.f ? 1.f / d0 : 0.f);
    float acc[8] = {0,0,0,0,0,0,0,0};
#pragma unroll
    for (int k = 0; k < KT; k++)
        for (int e = beg[k]; e < end[k]; e++) {
            float sc = esc[(size_t)e * 2 + head];
            float al = __expf(sc - mm) * iv;
            u16x8 fv = *(const u16x8*)(feat + (size_t)srcs[e] * 512 + lane * 8);
#pragma unroll
            for (int j = 0; j < 8; j++) acc[j] += al * b2f(fv[j]);
        }
    int di = lane * 8;
    f4 o0, o1;
#pragma unroll
    for (int j = 0; j < 4; j++) {
        o0[j] = fmaxf(acc[j] + gat_bias[di + j], 0.f);
        o1[j] = fmaxf(acc[4 + j] + gat_bias[di + 4 + j], 0.f);
    }
    *(f4*)(rst + (size_t)v * 512 + di) = o0;
    *(f4*)(rst + (size_t)v * 512 + di + 4) = o1;
}

// ---------- graph boundaries via binary search on sorted graph_ids ----------
__global__ void graph_bounds(const int* __restrict__ gids, int* __restrict__ goff) {
    int g = threadIdx.x;   // 128 threads, need 0..64
    if (g > GG) return;
    int lo = 0, hi = NN;
    while (lo < hi) { int mid = (lo + hi) >> 1; if (gids[mid] < g) lo = mid + 1; else hi = mid; }
    goff[g] = lo;
}

// ---------- per-graph partial sums of rst -> hgm (atomic, 8 chunks/graph) ----------
__global__ void graph_mean2(const float* __restrict__ rst, const int* __restrict__ goff,
                            float* __restrict__ hgm) {
    int g = blockIdx.x, yc = blockIdx.y, t = threadIdx.x;
    int beg = goff[g], end = goff[g + 1];
    float s0 = 0.f, s1 = 0.f;
    for (int n = beg + yc; n < end; n += 8) {
        s0 += rst[(size_t)n * 512 + t];
        s1 += rst[(size_t)n * 512 + 256 + t];
    }
    atomicAdd(&hgm[g * 512 + t], s0);
    atomicAdd(&hgm[g * 512 + 256 + t], s1);
}

// ---------- classify (divides by graph size) ----------
__global__ void classify(const float* __restrict__ hgm, const int* __restrict__ goff,
                         const float* __restrict__ cw, const float* __restrict__ cb,
                         float* __restrict__ out) {
    __shared__ float hl[512];
    int g = blockIdx.x, t = threadIdx.x;  // 64 threads
    int cntn = goff[g + 1] - goff[g];
    float inv = (cntn > 0) ? 1.f / (float)cntn : 0.f;
    for (int d = t; d < 512; d += 64) hl[d] = hgm[g * 512 + d] * inv;
    __syncthreads();
    if (t < 32) {
        int hd = t >> 4, c = t & 15;
        float acc = 0.f;
        for (int d = 0; d < 256; d++) acc += hl[hd * 256 + d] * cw[c * 256 + d];
        out[(g * 2 + hd) * NC + c] = acc + cb[c];
    }
}

static inline int cdiv(int a, int b) { return (a + b - 1) / b; }
static inline size_t alup(size_t x) { return (x + 255) & ~(size_t)255; }

extern "C" void kernel_launch(void* const* d_in, const int* in_sizes, int n_in,
                              void* d_out, int out_size, void* d_ws, size_t ws_size,
                              hipStream_t stream) {
    const float* in_feat   = (const float*)d_in[0];
    const int*   src       = (const int*)d_in[1];
    const int*   dst       = (const int*)d_in[2];
    const int*   etype     = (const int*)d_in[3];
    const int*   graph_ids = (const int*)d_in[4];
    const float* Wmsg      = (const float*)d_in[5];
    const float* bmsg      = (const float*)d_in[6];
    const float* w_ih      = (const float*)d_in[7];
    const float* w_hh      = (const float*)d_in[8];
    const float* b_ih      = (const float*)d_in[9];
    const float* b_hh      = (const float*)d_in[10];
    const float* fc_w      = (const float*)d_in[11];
    const float* attn_l    = (const float*)d_in[12];
    const float* attn_r    = (const float*)d_in[13];
    const float* gat_bias  = (const float*)d_in[14];
    const float* cw        = (const float*)d_in[15];
    const float* cb        = (const float*)d_in[16];
    float* out = (float*)d_out;

    char* p = (char*)d_ws;
    ushort* hbfA  = (ushort*)p; p += alup((size_t)NP * 512 * 2);
    ushort* hbfB  = (ushort*)p; p += alup((size_t)NP * 512 * 2);
    ushort* abf   = (ushort*)p; p += alup((size_t)NP * 512 * 2);
    ushort* S2    = (ushort*)p; p += alup((size_t)2 * NP * 512 * 2);  // gathered S pair / rz (NP x 1024) / rst f32
    ushort* wmsgT = (ushort*)p; p += alup((size_t)KT * 512 * 512 * 2);
    ushort* wihb  = (ushort*)p; p += alup((size_t)1536 * 512 * 2);
    ushort* whhb  = (ushort*)p; p += alup((size_t)1536 * 512 * 2);
    ushort* wrz   = (ushort*)p; p += alup((size_t)1024 * 1024 * 2);
    ushort* fcb   = (ushort*)p; p += alup((size_t)512 * 512 * 2);
    int*    cnt   = (int*)p;    p += alup((size_t)TOTKV * 4);
    int*    offs  = (int*)p;    p += alup(((size_t)TOTKV + 1) * 4);
    int*    cursor= (int*)p;    p += alup(((size_t)TOTKV + 1) * 4);
    float*  cntf  = (float*)p;  p += alup((size_t)TOTKV * 4);
    int*    bsum  = (int*)p;    p += alup((size_t)NBLK * 4);
    int*    boff  = (int*)p;    p += alup((size_t)NBLK * 4);
    int*    srcs_s= (int*)p;    p += alup((size_t)EE * 4);
    int*    dsts_s= (int*)p;    p += alup((size_t)EE * 4);
    float*  esc   = (float*)p;  p += alup((size_t)EE * 2 * 4);
    float*  el    = (float*)p;  p += alup((size_t)NN * 2 * 4);
    float*  er    = (float*)p;  p += alup((size_t)NN * 2 * 4);
    int*    goff  = (int*)p;    p += alup((size_t)(GG + 1) * 4);
    float*  hgm   = (float*)p;  p += alup((size_t)GG * 512 * 4);
    ushort* featbf = abf;          // alias: abf free after last gemm_gru
    float*  rst    = (float*)S2;   // alias: rz region free after last gemm_gru (same byte size)

    // ---- weight prep ----
    conv_msgT<<<dim3(16, 16, 4), 256, 0, stream>>>(Wmsg, wmsgT);
    conv_copy<<<cdiv(1536 * 512, 256), 256, 0, stream>>>(w_ih, wihb, 1536 * 512);
    conv_copy<<<cdiv(1536 * 512, 256), 256, 0, stream>>>(w_hh, whhb, 1536 * 512);
    build_wrz<<<cdiv(1024 * 1024, 256), 256, 0, stream>>>(w_ih, w_hh, wrz);
    conv_copy<<<cdiv(512 * 512, 256), 256, 0, stream>>>(fc_w, fcb, 512 * 512);

    // ---- CSR build ----
    hipMemsetAsync(cnt, 0, (size_t)TOTKV * 4, stream);
    count_edges<<<cdiv(EE, 256), 256, 0, stream>>>(etype, dst, cnt);
    scan_blk<<<NBLK, 512, 0, stream>>>(cnt, offs, cntf, bsum);
    scan_top<<<1, 64, 0, stream>>>(bsum, boff, offs);
    scan_add<<<NBLK, 512, 0, stream>>>(offs, boff);
    hipMemcpyAsync(cursor, offs, (size_t)TOTKV * 4, hipMemcpyDeviceToDevice, stream);
    fill_edges<<<cdiv(EE, 256), 256, 0, stream>>>(etype, dst, src, cursor, srcs_s, dsts_s);
    graph_bounds<<<1, 128, 0, stream>>>(graph_ids, goff);

    pad2<<<cdiv(NP * 64, 256), 256, 0, stream>>>(in_feat, hbfA);

    const ushort* win = wihb + (size_t)1024 * 512;   // n-gate rows of w_ih
    const ushort* whn = whhb + (size_t)1024 * 512;   // n-gate rows of w_hh

    ushort* hin = hbfA;
    ushort* hout = hbfB;
    for (int step = 0; step < NSTEPS; step++) {
        // step 0: h cols 256..511 are zero -> trim K on every GEMM touching h
        int ktMsgA = (step == 0) ? 256 : 512;     // per-segment K for msg gemms
        int ktMsg  = 2 * ktMsgA;
        int ktRZ   = (step == 0) ? 768 : 1024;    // abf(512) + h(256|512)
        int ktHN   = (step == 0) ? 256 : 512;
        // message passing: abf = sum_k S_k @ Wmsg_k^T + sum_k cnt_k*bmsg_k   (bf16)
        gather2<<<2 * NP / 4, 256, 0, stream>>>(offs, srcs_s, hin, S2, 0);
        gemm2<<<dim3(4, NP / 128), 256, 0, stream>>>(
            wmsgT, wmsgT + (size_t)1 * 262144, 512, S2, S2 + (size_t)NP * 512, ktMsgA, ktMsg,
            abf, 512, 0, nullptr, nullptr);
        gather2<<<2 * NP / 4, 256, 0, stream>>>(offs, srcs_s, hin, S2, 1);
        gemm2<<<dim3(4, NP / 128), 256, 0, stream>>>(
            wmsgT + (size_t)2 * 262144, wmsgT + (size_t)3 * 262144, 512, S2, S2 + (size_t)NP * 512, ktMsgA, ktMsg,
            abf, 512, 3, cntf, bmsg);
        // merged: rz = [abf|hin] @ Wrz^T -> S2 ; h_n = hin @ whn^T -> hout
        gemm_rzhn<<<dim3(12, NP / 128), 256, 0, stream>>>(
            wrz, whn, abf, hin, S2, hout, ktRZ, ktHN);
        // i_n GEMM + fused GRU epilogue -> hout = h_new
        gemm_gru<<<dim3(4, NP / 128), 256, 0, stream>>>(
            win, abf, S2, hin, b_ih, b_hh, hout);
        ushort* tmp = hin; hin = hout; hout = tmp;
    }
    // hin now holds final h (hbfA after 4 steps)

    norm_sig<<<NN, 64, 0, stream>>>(hin);
    // feat = h @ fc_w^T  (bf16) -> featbf (abf region)
    gemm2<<<dim3(4, NP / 128), 256, 0, stream>>>(
        fcb, fcb, 512, hin, hin, 512, 512, featbf, 512, 0, nullptr, nullptr);
    el_er2<<<NN, 64, 0, stream>>>(featbf, attn_l, attn_r, el, er);
    edge_scores<<<cdiv(EE, 256), 256, 0, stream>>>(srcs_s, dsts_s, el, er, esc);

    gat3<<<NN / 4, 256, 0, stream>>>(offs, srcs_s, esc, featbf, gat_bias, rst);
    hipMemsetAsync(hgm, 0, (size_t)GG * 512 * 4, stream);
    graph_mean2<<<dim3(GG, 8), 256, 0, stream>>>(rst, goff, hgm);
    classify<<<GG, 64, 0, stream>>>(hgm, goff, cw, cb, out);
}